// Round 11
// baseline (598.727 us; speedup 1.0000x reference)
//
#include <hip/hip_runtime.h>
#include <math.h>

#define VOCAB 32000
#define HDIM  512
#define NLAYERS 4
#define BATCH 32
#define TSTEPS 64
typedef unsigned long long ULL;

typedef __attribute__((ext_vector_type(8))) short bf16x8;
typedef __attribute__((ext_vector_type(4))) float f32x4;
typedef __attribute__((ext_vector_type(4))) unsigned int u32x4;

static __device__ __forceinline__ unsigned short f2b(float f) {
    union { float f; unsigned u; } v; v.f = f;
    return (unsigned short)((v.u + 0x7FFFu + ((v.u >> 16) & 1u)) >> 16);
}
static __device__ __forceinline__ float sigf(float x) { return 1.0f / (1.0f + __expf(-x)); }

// 16B coherence-point (L1+L2 bypass) load/store
static __device__ __forceinline__ u32x4 load16cp(const void* p) {
    u32x4 r;
    asm volatile("global_load_dwordx4 %0, %1, off sc0 sc1" : "=v"(r) : "v"(p) : "memory");
    return r;
}
static __device__ __forceinline__ void store16cp(void* p, u32x4 v) {
    asm volatile("global_store_dwordx4 %0, %1, off sc0 sc1" :: "v"(p), "v"(v) : "memory");
}
static __device__ __forceinline__ void waitvm0() {
    asm volatile("s_waitcnt vmcnt(0)" ::: "memory");
}

// packed offset of element (m,k) in a [32 rows][1024 k] bf16 operand stored in
// MFMA-fragment order: [k0=k/32][mi=m/16][lane][8]
static __device__ __forceinline__ int apack_off(int m, int k) {
    int k0 = k >> 5, mi = m >> 4;
    int lane = (m & 15) | (((k >> 3) & 3) << 4);
    return ((k0 * 2 + mi) * 64 + lane) * 8 + (k & 7);
}

// ---------------- weight prep (verified rounds 2-7) ----------------
__global__ void k_prep_w(const float* __restrict__ W_ih, const float* __restrict__ W_hh,
                         unsigned short* __restrict__ wp) {
    const int total = NLAYERS * 64 * 2 * 32 * 64 * 8;  // 8388608
    for (int idx = blockIdx.x * blockDim.x + threadIdx.x; idx < total;
         idx += gridDim.x * blockDim.x) {
        int sub = idx & 7, lane = (idx >> 3) & 63, k0 = (idx >> 9) & 31;
        int ni = (idx >> 14) & 1, bi = (idx >> 15) & 63, l = idx >> 21;
        int r = ni * 16 + (lane & 15);
        int k = k0 * 32 + ((lane >> 4) << 3) + sub;
        int j = (r & 3) * 512 + bi * 8 + (r >> 2);
        float v = (k < 512) ? W_ih[((size_t)l * 2048 + j) * 512 + k]
                            : W_hh[((size_t)l * 2048 + j) * 512 + (k - 512)];
        wp[idx] = f2b(v);
    }
}

__global__ void k_prep_bias(const float* __restrict__ b_ih, const float* __restrict__ b_hh,
                            float* __restrict__ bs) {
    int idx = blockIdx.x * blockDim.x + threadIdx.x;
    if (idx < NLAYERS * 64 * 32) {
        int r = idx & 31, bi = (idx >> 5) & 63, l = idx >> 11;
        int j = (r & 3) * 512 + bi * 8 + (r >> 2);
        bs[idx] = b_ih[l * 2048 + j] + b_hh[l * 2048 + j];
    }
}

// ---------------- W_cls -> bf16, MFMA-fragment packed (verified round 7) ----------------
__global__ void k_prep_wcls(const float* __restrict__ W_cls, unsigned short* __restrict__ wp) {
    int idx8 = blockIdx.x * blockDim.x + threadIdx.x;   // 2048000 chunks
    int lane = idx8 & 63, k0 = (idx8 >> 6) & 15, ni = (idx8 >> 10) & 1;
    int w = (idx8 >> 11) & 3, vt = idx8 >> 13;
    int v = vt * 128 + w * 32 + ni * 16 + (lane & 15);
    int kb = k0 * 32 + ((lane >> 4) << 3);
    const float* src = W_cls + (size_t)v * 512 + kb;
    float4 f0 = *(const float4*)(src);
    float4 f1 = *(const float4*)(src + 4);
    bf16x8 u;
    u[0] = (short)f2b(f0.x); u[1] = (short)f2b(f0.y);
    u[2] = (short)f2b(f0.z); u[3] = (short)f2b(f0.w);
    u[4] = (short)f2b(f1.x); u[5] = (short)f2b(f1.y);
    u[6] = (short)f2b(f1.z); u[7] = (short)f2b(f1.w);
    *(bf16x8*)(wp + (size_t)idx8 * 8) = u;
}

__global__ void k_embed(const float* __restrict__ emb, const int* __restrict__ dec,
                        float* __restrict__ seqF, unsigned short* __restrict__ seqBp) {
    int t = blockIdx.x;
    for (int i = threadIdx.x; i < BATCH * HDIM; i += blockDim.x) {
        int b = i >> 9, e = i & 511;
        int tok = dec[b * TSTEPS + t];
        float v = emb[(size_t)tok * HDIM + e];
        seqF[((size_t)t * BATCH + b) * HDIM + e] = v;
        seqBp[(size_t)t * 16384 + apack_off(b, e)] = f2b(v);
    }
}

__global__ void k_inith(const float* __restrict__ h0, unsigned short* __restrict__ apack) {
    int idx = blockIdx.x * blockDim.x + threadIdx.x;   // 65536
    int l = idx >> 14, b = (idx >> 9) & 31, d = idx & 511;
    apack[(size_t)(l * 2) * 32768 + apack_off(b, 512 + d)] =
        f2b(h0[((size_t)l * BATCH + b) * HDIM + d]);
}

// ---------------- persistent LSTM: flag pipeline, decongested ----------------
// 256 blocks (layer l = blk>>6, slice bi = blk&63) x 256 threads.
// Flags packed contiguous (4 IC lines per layer-set); ONLY wave 0 polls all three
// conditions. Staging/exports use 16B sc0+sc1 ops via inline asm. Residual outF
// block-major for contiguous 1KB store/load.
__global__ __launch_bounds__(256, 1) void k_lstm(
    unsigned short* apack,                    // [4][2][32768] bf16 fragment-packed [inp|h]
    const unsigned short* __restrict__ wpack,
    const float* __restrict__ bsum,
    const unsigned short* __restrict__ seqBp, // [64][16384] packed emb (read-only, cached)
    const float* __restrict__ seqF,           // [64][32][512] fp32 emb (read-only, cached)
    float* outF,                              // [8 keys][64 bi][256] fp32 residual exchange
    unsigned short* __restrict__ seqOut,      // [32][16][4][64][8] final layer out, packed
    const float* __restrict__ c0,
    float* __restrict__ outHT, float* __restrict__ outCT,
    unsigned* flags) {                        // [4][64] u32, contiguous
    const int l = blockIdx.x >> 6, bi = blockIdx.x & 63;
    const int wave = threadIdx.x >> 6, lane = threadIdx.x & 63;
    const int mi = wave >> 1, ni = wave & 1;
    const int cb = threadIdx.x >> 3, dsl = threadIdx.x & 7;
    const int d = bi * 8 + dsl;

    __shared__ __align__(16) short sW[32768];    // 64 KB W slice
    __shared__ __align__(16) short sA[32768];    // 64 KB A staging
    __shared__ __align__(16) float sG[1024];     //  4 KB gates
    __shared__ __align__(16) short sHexH[256];   // h export repack (32b x 8d)
    __shared__ __align__(16) short sHexO[256];   // o export repack

    {   // stationary W slice -> LDS (cached reads, once)
        const unsigned short* wp = wpack + (size_t)blockIdx.x * 32768;
        #pragma unroll
        for (int i = 0; i < 16; ++i) {
            int off = (i * 256 + threadIdx.x) * 8;
            *(bf16x8*)(sW + off) = *(const bf16x8*)(wp + off);
        }
    }
    float4 bias = *(const float4*)(bsum + blockIdx.x * 32 + dsl * 4);
    float c = c0[((size_t)l * BATCH + cb) * HDIM + d];

    unsigned short* A0 = apack + (size_t)(l * 2 + 0) * 32768;
    unsigned short* A1 = apack + (size_t)(l * 2 + 1) * 32768;

    for (int t = 0; t < TSTEPS; ++t) {
        // ---- layer 0: prestage static emb inp-half (no flag dependency) ----
        if (l == 0) {
            const u32x4* sp = (const u32x4*)(seqBp + (size_t)t * 16384);
            u32x4* dA = (u32x4*)sA;
            #pragma unroll
            for (int i = 0; i < 8; ++i)
                dA[i * 256 + threadIdx.x] = sp[i * 256 + threadIdx.x];
        }

        // ---- flow control: wave 0 polls all 3 conditions on packed flags ----
        if (threadIdx.x < 64) {
            unsigned n0 = (unsigned)t;
            unsigned n1 = (unsigned)(t + 1);
            unsigned n2 = (unsigned)(t > 0 ? t - 1 : 0);
            const unsigned* f0 = flags + l * 64 + lane;
            for (;;) {
                unsigned v0 = __hip_atomic_load(f0, __ATOMIC_RELAXED, __HIP_MEMORY_SCOPE_AGENT);
                unsigned v1 = (l > 0) ? __hip_atomic_load(f0 - 64, __ATOMIC_RELAXED,
                                                          __HIP_MEMORY_SCOPE_AGENT) : 0xFFFFFFFFu;
                unsigned v2 = (l < 3) ? __hip_atomic_load(f0 + 64, __ATOMIC_RELAXED,
                                                          __HIP_MEMORY_SCOPE_AGENT) : 0xFFFFFFFFu;
                if (v0 >= n0 && v1 >= n1 && v2 >= n2) break;
                __builtin_amdgcn_s_sleep(1);
            }
        }
        __syncthreads();

        // ---- residual input (block-major outF: contiguous 1KB) ----
        float inpf;
        if (l == 0) inpf = seqF[((size_t)t * BATCH + cb) * HDIM + d];
        else inpf = __hip_atomic_load(&outF[((size_t)(l * 2 + (t & 1)) * 64 + bi) * 256 + threadIdx.x],
                                      __ATOMIC_RELAXED, __HIP_MEMORY_SCOPE_AGENT);

        // ---- stage A(l, t&1) -> LDS via 16B coherence-point loads ----
        const unsigned short* Ab = (t & 1) ? A1 : A0;
        {
            u32x4* dA = (u32x4*)sA;
            if (l == 0) {
                u32x4 tmp[8];
                #pragma unroll
                for (int i = 0; i < 8; ++i)
                    tmp[i] = load16cp((const char*)Ab + ((8 + i) * 256 + threadIdx.x) * 16);
                waitvm0();
                #pragma unroll
                for (int i = 0; i < 8; ++i)
                    dA[(8 + i) * 256 + threadIdx.x] = tmp[i];
            } else {
                u32x4 tmp[16];
                #pragma unroll
                for (int i = 0; i < 16; ++i)
                    tmp[i] = load16cp((const char*)Ab + (i * 256 + threadIdx.x) * 16);
                waitvm0();
                #pragma unroll
                for (int i = 0; i < 16; ++i)
                    dA[i * 256 + threadIdx.x] = tmp[i];
            }
        }
        __syncthreads();

        // ---- gates = A @ Wslice^T (each wave one 16x16 tile, K=1024) ----
        f32x4 acc = {0.f, 0.f, 0.f, 0.f};
        const short* abase = sA + mi * 512 + lane * 8;
        const short* wbase = sW + ni * 16384 + lane * 8;
        #pragma unroll
        for (int k0 = 0; k0 < 32; ++k0)
            acc = __builtin_amdgcn_mfma_f32_16x16x32_bf16(
                *(const bf16x8*)(abase + k0 * 1024),
                *(const bf16x8*)(wbase + k0 * 512), acc, 0, 0, 0);

        int gb = mi * 16 + (lane >> 4) * 4;
        int gr = ni * 16 + (lane & 15);
        #pragma unroll
        for (int r = 0; r < 4; ++r) sG[(gb + r) * 32 + gr] = acc[r];
        __syncthreads();

        // ---- cell update (thread owns (cb, d)) ----
        float4 g4 = *(const float4*)(sG + cb * 32 + dsl * 4);
        float gi = g4.x + bias.x, gf = g4.y + bias.y;
        float gg = g4.z + bias.z, go = g4.w + bias.w;
        float ci = sigf(gf) * c + sigf(gi) * tanhf(gg);
        float hi = sigf(go) * tanhf(ci);
        c = ci;
        float o = hi + inpf;

        sHexH[threadIdx.x] = f2b(hi);
        sHexO[threadIdx.x] = f2b(o);
        if (l < 3)    // block-major residual: contiguous 1KB sc1 store
            __hip_atomic_store(&outF[((size_t)((l + 1) * 2 + (t & 1)) * 64 + bi) * 256 + threadIdx.x],
                               o, __ATOMIC_RELAXED, __HIP_MEMORY_SCOPE_AGENT);
        if (t == TSTEPS - 1) {
            outHT[((size_t)l * BATCH + cb) * HDIM + d] = hi;
            outCT[((size_t)l * BATCH + cb) * HDIM + d] = ci;
        }
        __syncthreads();

        // ---- export: 16B sc1 stores (layouts verified round 7) ----
        unsigned short* An = ((t + 1) & 1) ? A1 : A0;
        int tid = threadIdx.x;
        if (tid < 32) {
            int X = (tid & 15) | ((bi & 3) << 4);
            int chunk = (16 + (bi >> 2)) * 2 + (tid >> 4);
            store16cp((char*)An + chunk * 1024 + X * 16, ((const u32x4*)sHexH)[tid]);
        } else if (tid >= 64 && tid < 96) {
            int t2 = tid - 64;
            int X = (t2 & 15) | ((bi & 3) << 4);
            if (l < 3) {
                unsigned short* Anx = apack + (size_t)((l + 1) * 2 + (t & 1)) * 32768;
                int chunk = (bi >> 2) * 2 + (t2 >> 4);
                store16cp((char*)Anx + chunk * 1024 + X * 16, ((const u32x4*)sHexO)[t2]);
            } else {
                // fragment-packed classifier A-operand (plain store; kernel-end flush)
                int idx16 = ((t2 * 16 + (bi >> 2)) * 4 + (t >> 4)) * 64 +
                            ((t & 15) | ((bi & 3) << 4));
                ((u32x4*)seqOut)[idx16] = ((const u32x4*)sHexO)[t2];
            }
        }

        // own stores ack'd at coherence point, then publish flag = t+1
        waitvm0();
        __syncthreads();
        if (threadIdx.x == 0)
            __hip_atomic_store(&flags[l * 64 + bi], (unsigned)(t + 1),
                               __ATOMIC_RELAXED, __HIP_MEMORY_SCOPE_AGENT);
    }
}

// ---------------- fused classifier + log_softmax over T, packed operands (verified r7) ----
__global__ __launch_bounds__(256) void k_cls(
    const unsigned short* __restrict__ Ap,   // [32][16][4][64][8] packed seq
    const unsigned short* __restrict__ Wp,   // [250][4][2][16][64][8] packed W_cls
    float* __restrict__ out) {               // [B][T][V]
    int b = blockIdx.x & 31;
    int vt = blockIdx.x >> 5;
    int wave = threadIdx.x >> 6;
    int lane = threadIdx.x & 63;

    __shared__ float sL[64 * 132];   // padded stride 132 (33 KB)

    const unsigned short* abase = Ap + (size_t)b * 32768 + lane * 8;
    const unsigned short* wbase = Wp + (size_t)(vt * 4 + wave) * 16384 + lane * 8;

    f32x4 acc[4][2];
    #pragma unroll
    for (int i = 0; i < 4; ++i)
        #pragma unroll
        for (int j = 0; j < 2; ++j) acc[i][j] = (f32x4)(0.0f);

    #pragma unroll 4
    for (int k0 = 0; k0 < 16; ++k0) {
        bf16x8 a[4], bb[2];
        #pragma unroll
        for (int mi = 0; mi < 4; ++mi)
            a[mi] = *(const bf16x8*)(abase + (k0 * 4 + mi) * 512);
        #pragma unroll
        for (int ni = 0; ni < 2; ++ni)
            bb[ni] = *(const bf16x8*)(wbase + ni * 8192 + k0 * 512);
        #pragma unroll
        for (int mi = 0; mi < 4; ++mi)
            #pragma unroll
            for (int ni = 0; ni < 2; ++ni)
                acc[mi][ni] = __builtin_amdgcn_mfma_f32_16x16x32_bf16(a[mi], bb[ni], acc[mi][ni], 0, 0, 0);
    }

    #pragma unroll
    for (int ni = 0; ni < 2; ++ni) {
        float m = -1e30f;
        #pragma unroll
        for (int mi = 0; mi < 4; ++mi)
            #pragma unroll
            for (int r = 0; r < 4; ++r) m = fmaxf(m, acc[mi][ni][r]);
        m = fmaxf(m, __shfl_xor(m, 16));
        m = fmaxf(m, __shfl_xor(m, 32));
        float s = 0.f;
        #pragma unroll
        for (int mi = 0; mi < 4; ++mi)
            #pragma unroll
            for (int r = 0; r < 4; ++r) s += expf(acc[mi][ni][r] - m);
        s += __shfl_xor(s, 16);
        s += __shfl_xor(s, 32);
        float logZ = m + logf(s);
        int col = wave * 32 + ni * 16 + (lane & 15);
        #pragma unroll
        for (int mi = 0; mi < 4; ++mi) {
            #pragma unroll
            for (int r = 0; r < 4; ++r) {
                int row = mi * 16 + (lane >> 4) * 4 + r;
                sL[row * 132 + col] = acc[mi][ni][r] - logZ;
            }
        }
    }
    __syncthreads();

    float* obase = out + (size_t)b * TSTEPS * VOCAB + vt * 128;
    #pragma unroll
    for (int it = 0; it < 8; ++it) {
        int idx = it * 256 + threadIdx.x;
        int row = idx >> 5, c4 = (idx & 31) * 4;
        float4 val = *(const float4*)(sL + row * 132 + c4);
        *(float4*)(obase + (size_t)row * VOCAB + c4) = val;
    }
}

extern "C" void kernel_launch(void* const* d_in, const int* in_sizes, int n_in,
                              void* d_out, int out_size, void* d_ws, size_t ws_size,
                              hipStream_t stream) {
    const int*   dec   = (const int*)d_in[1];
    const float* h0    = (const float*)d_in[2];
    const float* c0    = (const float*)d_in[3];
    const float* emb   = (const float*)d_in[4];
    const float* W_ih  = (const float*)d_in[5];
    const float* W_hh  = (const float*)d_in[6];
    const float* b_ih  = (const float*)d_in[7];
    const float* b_hh  = (const float*)d_in[8];
    const float* W_cls = (const float*)d_in[9];

    const int LBH = NLAYERS * BATCH * HDIM;           // 65536
    const size_t BTV = (size_t)BATCH * TSTEPS * VOCAB;

    char* ws = (char*)d_ws;
    size_t off = 0;
    auto alloc = [&](size_t bytes) -> void* {
        void* p = ws + off;
        off = (off + bytes + 255) & ~(size_t)255;
        return p;
    };
    unsigned short* wpack  = (unsigned short*)alloc((size_t)NLAYERS * 64 * 2 * 32 * 64 * 8 * 2);
    float*          bsum   = (float*)alloc((size_t)NLAYERS * 64 * 32 * 4);
    unsigned short* wpackC = (unsigned short*)alloc((size_t)VOCAB * HDIM * 2);
    float*          seqF   = (float*)alloc((size_t)TSTEPS * BATCH * HDIM * 4);
    unsigned short* seqBp  = (unsigned short*)alloc((size_t)TSTEPS * 16384 * 2);
    unsigned short* apack  = (unsigned short*)alloc((size_t)NLAYERS * 2 * 32768 * 2);
    float*          outF   = (float*)alloc((size_t)8 * 64 * 256 * 4);
    unsigned short* apackC = (unsigned short*)alloc((size_t)TSTEPS * BATCH * HDIM * 2);
    unsigned*       flags  = (unsigned*)alloc(1024);

    k_prep_w<<<4096, 256, 0, stream>>>(W_ih, W_hh, wpack);
    k_prep_bias<<<32, 256, 0, stream>>>(b_ih, b_hh, bsum);
    k_prep_wcls<<<8000, 256, 0, stream>>>(W_cls, wpackC);
    k_embed<<<TSTEPS, 256, 0, stream>>>(emb, dec, seqF, seqBp);
    k_inith<<<256, 256, 0, stream>>>(h0, apack);
    hipMemsetAsync(flags, 0, 1024, stream);

    k_lstm<<<256, 256, 0, stream>>>(apack, wpack, bsum, seqBp, seqF, outF, apackC,
                                    c0,
                                    (float*)d_out + BTV,
                                    (float*)d_out + BTV + LBH,
                                    flags);

    k_cls<<<250 * 32, 256, 0, stream>>>(apackC, wpackC, (float*)d_out);
}

// Round 12
// 597.900 us; speedup vs baseline: 1.0014x; 1.0014x over previous
//
#include <hip/hip_runtime.h>
#include <math.h>

#define VOCAB 32000
#define HDIM  512
#define NLAYERS 4
#define BATCH 32
#define TSTEPS 64
typedef unsigned long long ULL;

typedef __attribute__((ext_vector_type(8))) short bf16x8;
typedef __attribute__((ext_vector_type(4))) float f32x4;
typedef __attribute__((ext_vector_type(4))) unsigned int u32x4;

static __device__ __forceinline__ unsigned short f2b(float f) {
    union { float f; unsigned u; } v; v.f = f;
    return (unsigned short)((v.u + 0x7FFFu + ((v.u >> 16) & 1u)) >> 16);
}
static __device__ __forceinline__ float sigf(float x) { return 1.0f / (1.0f + __expf(-x)); }

// 16B coherence-point (L1+L2 bypass) load/store
static __device__ __forceinline__ u32x4 load16cp(const void* p) {
    u32x4 r;
    asm volatile("global_load_dwordx4 %0, %1, off sc0 sc1" : "=v"(r) : "v"(p) : "memory");
    return r;
}
static __device__ __forceinline__ void store16cp(void* p, u32x4 v) {
    asm volatile("global_store_dwordx4 %0, %1, off sc0 sc1" :: "v"(p), "v"(v) : "memory");
}
static __device__ __forceinline__ void waitvm0() {
    asm volatile("s_waitcnt vmcnt(0)" ::: "memory");
}

// packed offset of element (m,k) in a [32 rows][1024 k] bf16 operand stored in
// MFMA-fragment order: [k0=k/32][mi=m/16][lane][8]
static __device__ __forceinline__ int apack_off(int m, int k) {
    int k0 = k >> 5, mi = m >> 4;
    int lane = (m & 15) | (((k >> 3) & 3) << 4);
    return ((k0 * 2 + mi) * 64 + lane) * 8 + (k & 7);
}

// ---------------- weight prep (verified rounds 2-7) ----------------
__global__ void k_prep_w(const float* __restrict__ W_ih, const float* __restrict__ W_hh,
                         unsigned short* __restrict__ wp) {
    const int total = NLAYERS * 64 * 2 * 32 * 64 * 8;  // 8388608
    for (int idx = blockIdx.x * blockDim.x + threadIdx.x; idx < total;
         idx += gridDim.x * blockDim.x) {
        int sub = idx & 7, lane = (idx >> 3) & 63, k0 = (idx >> 9) & 31;
        int ni = (idx >> 14) & 1, bi = (idx >> 15) & 63, l = idx >> 21;
        int r = ni * 16 + (lane & 15);
        int k = k0 * 32 + ((lane >> 4) << 3) + sub;
        int j = (r & 3) * 512 + bi * 8 + (r >> 2);
        float v = (k < 512) ? W_ih[((size_t)l * 2048 + j) * 512 + k]
                            : W_hh[((size_t)l * 2048 + j) * 512 + (k - 512)];
        wp[idx] = f2b(v);
    }
}

__global__ void k_prep_bias(const float* __restrict__ b_ih, const float* __restrict__ b_hh,
                            float* __restrict__ bs) {
    int idx = blockIdx.x * blockDim.x + threadIdx.x;
    if (idx < NLAYERS * 64 * 32) {
        int r = idx & 31, bi = (idx >> 5) & 63, l = idx >> 11;
        int j = (r & 3) * 512 + bi * 8 + (r >> 2);
        bs[idx] = b_ih[l * 2048 + j] + b_hh[l * 2048 + j];
    }
}

// ---------------- W_cls -> bf16, MFMA-fragment packed (verified round 7) ----------------
__global__ void k_prep_wcls(const float* __restrict__ W_cls, unsigned short* __restrict__ wp) {
    int idx8 = blockIdx.x * blockDim.x + threadIdx.x;   // 2048000 chunks
    int lane = idx8 & 63, k0 = (idx8 >> 6) & 15, ni = (idx8 >> 10) & 1;
    int w = (idx8 >> 11) & 3, vt = idx8 >> 13;
    int v = vt * 128 + w * 32 + ni * 16 + (lane & 15);
    int kb = k0 * 32 + ((lane >> 4) << 3);
    const float* src = W_cls + (size_t)v * 512 + kb;
    float4 f0 = *(const float4*)(src);
    float4 f1 = *(const float4*)(src + 4);
    bf16x8 u;
    u[0] = (short)f2b(f0.x); u[1] = (short)f2b(f0.y);
    u[2] = (short)f2b(f0.z); u[3] = (short)f2b(f0.w);
    u[4] = (short)f2b(f1.x); u[5] = (short)f2b(f1.y);
    u[6] = (short)f2b(f1.z); u[7] = (short)f2b(f1.w);
    *(bf16x8*)(wp + (size_t)idx8 * 8) = u;
}

__global__ void k_embed(const float* __restrict__ emb, const int* __restrict__ dec,
                        float* __restrict__ seqF, unsigned short* __restrict__ seqBp) {
    int t = blockIdx.x;
    for (int i = threadIdx.x; i < BATCH * HDIM; i += blockDim.x) {
        int b = i >> 9, e = i & 511;
        int tok = dec[b * TSTEPS + t];
        float v = emb[(size_t)tok * HDIM + e];
        seqF[((size_t)t * BATCH + b) * HDIM + e] = v;
        seqBp[(size_t)t * 16384 + apack_off(b, e)] = f2b(v);
    }
}

__global__ void k_inith(const float* __restrict__ h0, unsigned short* __restrict__ apack) {
    int idx = blockIdx.x * blockDim.x + threadIdx.x;   // 65536
    int l = idx >> 14, b = (idx >> 9) & 31, d = idx & 511;
    apack[(size_t)(l * 2) * 32768 + apack_off(b, 512 + d)] =
        f2b(h0[((size_t)l * BATCH + b) * HDIM + d]);
}

// ---------------- persistent LSTM: flag pipeline, decongested ----------------
// 256 blocks (layer l = blk>>6, slice bi = blk&63) x 256 threads.
// Flags packed contiguous (4 IC lines per layer-set); ONLY wave 0 polls all three
// conditions. Staging/exports use 16B sc0+sc1 ops via inline asm. Residual outF
// block-major for contiguous 1KB store/load.
__global__ __launch_bounds__(256, 1) void k_lstm(
    unsigned short* apack,                    // [4][2][32768] bf16 fragment-packed [inp|h]
    const unsigned short* __restrict__ wpack,
    const float* __restrict__ bsum,
    const unsigned short* __restrict__ seqBp, // [64][16384] packed emb (read-only, cached)
    const float* __restrict__ seqF,           // [64][32][512] fp32 emb (read-only, cached)
    float* outF,                              // [8 keys][64 bi][256] fp32 residual exchange
    unsigned short* __restrict__ seqOut,      // [32][16][4][64][8] final layer out, packed
    const float* __restrict__ c0,
    float* __restrict__ outHT, float* __restrict__ outCT,
    unsigned* flags) {                        // [4][64] u32, contiguous
    const int l = blockIdx.x >> 6, bi = blockIdx.x & 63;
    const int wave = threadIdx.x >> 6, lane = threadIdx.x & 63;
    const int mi = wave >> 1, ni = wave & 1;
    const int cb = threadIdx.x >> 3, dsl = threadIdx.x & 7;
    const int d = bi * 8 + dsl;

    __shared__ __align__(16) short sW[32768];    // 64 KB W slice
    __shared__ __align__(16) short sA[32768];    // 64 KB A staging
    __shared__ __align__(16) float sG[1024];     //  4 KB gates
    __shared__ __align__(16) short sHexH[256];   // h export repack (32b x 8d)
    __shared__ __align__(16) short sHexO[256];   // o export repack

    {   // stationary W slice -> LDS (cached reads, once)
        const unsigned short* wp = wpack + (size_t)blockIdx.x * 32768;
        #pragma unroll
        for (int i = 0; i < 16; ++i) {
            int off = (i * 256 + threadIdx.x) * 8;
            *(bf16x8*)(sW + off) = *(const bf16x8*)(wp + off);
        }
    }
    float4 bias = *(const float4*)(bsum + blockIdx.x * 32 + dsl * 4);
    float c = c0[((size_t)l * BATCH + cb) * HDIM + d];

    unsigned short* A0 = apack + (size_t)(l * 2 + 0) * 32768;
    unsigned short* A1 = apack + (size_t)(l * 2 + 1) * 32768;

    for (int t = 0; t < TSTEPS; ++t) {
        // ---- layer 0: prestage static emb inp-half (no flag dependency) ----
        if (l == 0) {
            const u32x4* sp = (const u32x4*)(seqBp + (size_t)t * 16384);
            u32x4* dA = (u32x4*)sA;
            #pragma unroll
            for (int i = 0; i < 8; ++i)
                dA[i * 256 + threadIdx.x] = sp[i * 256 + threadIdx.x];
        }

        // ---- flow control: wave 0 polls all 3 conditions on packed flags ----
        if (threadIdx.x < 64) {
            unsigned n0 = (unsigned)t;
            unsigned n1 = (unsigned)(t + 1);
            unsigned n2 = (unsigned)(t > 0 ? t - 1 : 0);
            const unsigned* f0 = flags + l * 64 + lane;
            for (;;) {
                unsigned v0 = __hip_atomic_load(f0, __ATOMIC_RELAXED, __HIP_MEMORY_SCOPE_AGENT);
                unsigned v1 = (l > 0) ? __hip_atomic_load(f0 - 64, __ATOMIC_RELAXED,
                                                          __HIP_MEMORY_SCOPE_AGENT) : 0xFFFFFFFFu;
                unsigned v2 = (l < 3) ? __hip_atomic_load(f0 + 64, __ATOMIC_RELAXED,
                                                          __HIP_MEMORY_SCOPE_AGENT) : 0xFFFFFFFFu;
                if (v0 >= n0 && v1 >= n1 && v2 >= n2) break;
                __builtin_amdgcn_s_sleep(1);
            }
        }
        __syncthreads();

        // ---- residual input (block-major outF: contiguous 1KB) ----
        float inpf;
        if (l == 0) inpf = seqF[((size_t)t * BATCH + cb) * HDIM + d];
        else inpf = __hip_atomic_load(&outF[((size_t)(l * 2 + (t & 1)) * 64 + bi) * 256 + threadIdx.x],
                                      __ATOMIC_RELAXED, __HIP_MEMORY_SCOPE_AGENT);

        // ---- stage A(l, t&1) -> LDS via 16B coherence-point loads ----
        const unsigned short* Ab = (t & 1) ? A1 : A0;
        {
            u32x4* dA = (u32x4*)sA;
            if (l == 0) {
                u32x4 tmp[8];
                #pragma unroll
                for (int i = 0; i < 8; ++i)
                    tmp[i] = load16cp((const char*)Ab + ((8 + i) * 256 + threadIdx.x) * 16);
                waitvm0();
                #pragma unroll
                for (int i = 0; i < 8; ++i)
                    dA[(8 + i) * 256 + threadIdx.x] = tmp[i];
            } else {
                u32x4 tmp[16];
                #pragma unroll
                for (int i = 0; i < 16; ++i)
                    tmp[i] = load16cp((const char*)Ab + (i * 256 + threadIdx.x) * 16);
                waitvm0();
                #pragma unroll
                for (int i = 0; i < 16; ++i)
                    dA[i * 256 + threadIdx.x] = tmp[i];
            }
        }
        __syncthreads();

        // ---- gates = A @ Wslice^T (each wave one 16x16 tile, K=1024) ----
        f32x4 acc = {0.f, 0.f, 0.f, 0.f};
        const short* abase = sA + mi * 512 + lane * 8;
        const short* wbase = sW + ni * 16384 + lane * 8;
        #pragma unroll
        for (int k0 = 0; k0 < 32; ++k0)
            acc = __builtin_amdgcn_mfma_f32_16x16x32_bf16(
                *(const bf16x8*)(abase + k0 * 1024),
                *(const bf16x8*)(wbase + k0 * 512), acc, 0, 0, 0);

        int gb = mi * 16 + (lane >> 4) * 4;
        int gr = ni * 16 + (lane & 15);
        #pragma unroll
        for (int r = 0; r < 4; ++r) sG[(gb + r) * 32 + gr] = acc[r];
        __syncthreads();

        // ---- cell update (thread owns (cb, d)) ----
        float4 g4 = *(const float4*)(sG + cb * 32 + dsl * 4);
        float gi = g4.x + bias.x, gf = g4.y + bias.y;
        float gg = g4.z + bias.z, go = g4.w + bias.w;
        float ci = sigf(gf) * c + sigf(gi) * tanhf(gg);
        float hi = sigf(go) * tanhf(ci);
        c = ci;
        float o = hi + inpf;

        sHexH[threadIdx.x] = f2b(hi);
        sHexO[threadIdx.x] = f2b(o);
        if (l < 3)    // block-major residual: contiguous 1KB sc1 store
            __hip_atomic_store(&outF[((size_t)((l + 1) * 2 + (t & 1)) * 64 + bi) * 256 + threadIdx.x],
                               o, __ATOMIC_RELAXED, __HIP_MEMORY_SCOPE_AGENT);
        if (t == TSTEPS - 1) {
            outHT[((size_t)l * BATCH + cb) * HDIM + d] = hi;
            outCT[((size_t)l * BATCH + cb) * HDIM + d] = ci;
        }
        __syncthreads();

        // ---- export: 16B sc1 stores (layouts verified round 7) ----
        unsigned short* An = ((t + 1) & 1) ? A1 : A0;
        int tid = threadIdx.x;
        if (tid < 32) {
            int X = (tid & 15) | ((bi & 3) << 4);
            int chunk = (16 + (bi >> 2)) * 2 + (tid >> 4);
            store16cp((char*)An + chunk * 1024 + X * 16, ((const u32x4*)sHexH)[tid]);
        } else if (tid >= 64 && tid < 96) {
            int t2 = tid - 64;
            int X = (t2 & 15) | ((bi & 3) << 4);
            if (l < 3) {
                unsigned short* Anx = apack + (size_t)((l + 1) * 2 + (t & 1)) * 32768;
                int chunk = (bi >> 2) * 2 + (t2 >> 4);
                store16cp((char*)Anx + chunk * 1024 + X * 16, ((const u32x4*)sHexO)[t2]);
            } else {
                // fragment-packed classifier A-operand (plain store; kernel-end flush)
                int idx16 = ((t2 * 16 + (bi >> 2)) * 4 + (t >> 4)) * 64 +
                            ((t & 15) | ((bi & 3) << 4));
                ((u32x4*)seqOut)[idx16] = ((const u32x4*)sHexO)[t2];
            }
        }

        // own stores ack'd at coherence point, then publish flag = t+1
        waitvm0();
        __syncthreads();
        if (threadIdx.x == 0)
            __hip_atomic_store(&flags[l * 64 + bi], (unsigned)(t + 1),
                               __ATOMIC_RELAXED, __HIP_MEMORY_SCOPE_AGENT);
    }
}

// ---------------- fused classifier + log_softmax over T, packed operands (verified r7) ----
__global__ __launch_bounds__(256) void k_cls(
    const unsigned short* __restrict__ Ap,   // [32][16][4][64][8] packed seq
    const unsigned short* __restrict__ Wp,   // [250][4][2][16][64][8] packed W_cls
    float* __restrict__ out) {               // [B][T][V]
    int b = blockIdx.x & 31;
    int vt = blockIdx.x >> 5;
    int wave = threadIdx.x >> 6;
    int lane = threadIdx.x & 63;

    __shared__ float sL[64 * 132];   // padded stride 132 (33 KB)

    const unsigned short* abase = Ap + (size_t)b * 32768 + lane * 8;
    const unsigned short* wbase = Wp + (size_t)(vt * 4 + wave) * 16384 + lane * 8;

    f32x4 acc[4][2];
    #pragma unroll
    for (int i = 0; i < 4; ++i)
        #pragma unroll
        for (int j = 0; j < 2; ++j) acc[i][j] = (f32x4)(0.0f);

    #pragma unroll 4
    for (int k0 = 0; k0 < 16; ++k0) {
        bf16x8 a[4], bb[2];
        #pragma unroll
        for (int mi = 0; mi < 4; ++mi)
            a[mi] = *(const bf16x8*)(abase + (k0 * 4 + mi) * 512);
        #pragma unroll
        for (int ni = 0; ni < 2; ++ni)
            bb[ni] = *(const bf16x8*)(wbase + ni * 8192 + k0 * 512);
        #pragma unroll
        for (int mi = 0; mi < 4; ++mi)
            #pragma unroll
            for (int ni = 0; ni < 2; ++ni)
                acc[mi][ni] = __builtin_amdgcn_mfma_f32_16x16x32_bf16(a[mi], bb[ni], acc[mi][ni], 0, 0, 0);
    }

    #pragma unroll
    for (int ni = 0; ni < 2; ++ni) {
        float m = -1e30f;
        #pragma unroll
        for (int mi = 0; mi < 4; ++mi)
            #pragma unroll
            for (int r = 0; r < 4; ++r) m = fmaxf(m, acc[mi][ni][r]);
        m = fmaxf(m, __shfl_xor(m, 16));
        m = fmaxf(m, __shfl_xor(m, 32));
        float s = 0.f;
        #pragma unroll
        for (int mi = 0; mi < 4; ++mi)
            #pragma unroll
            for (int r = 0; r < 4; ++r) s += expf(acc[mi][ni][r] - m);
        s += __shfl_xor(s, 16);
        s += __shfl_xor(s, 32);
        float logZ = m + logf(s);
        int col = wave * 32 + ni * 16 + (lane & 15);
        #pragma unroll
        for (int mi = 0; mi < 4; ++mi) {
            #pragma unroll
            for (int r = 0; r < 4; ++r) {
                int row = mi * 16 + (lane >> 4) * 4 + r;
                sL[row * 132 + col] = acc[mi][ni][r] - logZ;
            }
        }
    }
    __syncthreads();

    float* obase = out + (size_t)b * TSTEPS * VOCAB + vt * 128;
    #pragma unroll
    for (int it = 0; it < 8; ++it) {
        int idx = it * 256 + threadIdx.x;
        int row = idx >> 5, c4 = (idx & 31) * 4;
        float4 val = *(const float4*)(sL + row * 132 + c4);
        *(float4*)(obase + (size_t)row * VOCAB + c4) = val;
    }
}

extern "C" void kernel_launch(void* const* d_in, const int* in_sizes, int n_in,
                              void* d_out, int out_size, void* d_ws, size_t ws_size,
                              hipStream_t stream) {
    const int*   dec   = (const int*)d_in[1];
    const float* h0    = (const float*)d_in[2];
    const float* c0    = (const float*)d_in[3];
    const float* emb   = (const float*)d_in[4];
    const float* W_ih  = (const float*)d_in[5];
    const float* W_hh  = (const float*)d_in[6];
    const float* b_ih  = (const float*)d_in[7];
    const float* b_hh  = (const float*)d_in[8];
    const float* W_cls = (const float*)d_in[9];

    const int LBH = NLAYERS * BATCH * HDIM;           // 65536
    const size_t BTV = (size_t)BATCH * TSTEPS * VOCAB;

    char* ws = (char*)d_ws;
    size_t off = 0;
    auto alloc = [&](size_t bytes) -> void* {
        void* p = ws + off;
        off = (off + bytes + 255) & ~(size_t)255;
        return p;
    };
    unsigned short* wpack  = (unsigned short*)alloc((size_t)NLAYERS * 64 * 2 * 32 * 64 * 8 * 2);
    float*          bsum   = (float*)alloc((size_t)NLAYERS * 64 * 32 * 4);
    unsigned short* wpackC = (unsigned short*)alloc((size_t)VOCAB * HDIM * 2);
    float*          seqF   = (float*)alloc((size_t)TSTEPS * BATCH * HDIM * 4);
    unsigned short* seqBp  = (unsigned short*)alloc((size_t)TSTEPS * 16384 * 2);
    unsigned short* apack  = (unsigned short*)alloc((size_t)NLAYERS * 2 * 32768 * 2);
    float*          outF   = (float*)alloc((size_t)8 * 64 * 256 * 4);
    unsigned short* apackC = (unsigned short*)alloc((size_t)TSTEPS * BATCH * HDIM * 2);
    unsigned*       flags  = (unsigned*)alloc(1024);

    k_prep_w<<<4096, 256, 0, stream>>>(W_ih, W_hh, wpack);
    k_prep_bias<<<32, 256, 0, stream>>>(b_ih, b_hh, bsum);
    k_prep_wcls<<<8000, 256, 0, stream>>>(W_cls, wpackC);
    k_embed<<<TSTEPS, 256, 0, stream>>>(emb, dec, seqF, seqBp);
    k_inith<<<256, 256, 0, stream>>>(h0, apack);
    hipMemsetAsync(flags, 0, 1024, stream);

    k_lstm<<<256, 256, 0, stream>>>(apack, wpack, bsum, seqBp, seqF, outF, apackC,
                                    c0,
                                    (float*)d_out + BTV,
                                    (float*)d_out + BTV + LBH,
                                    flags);

    k_cls<<<250 * 32, 256, 0, stream>>>(apackC, wpackC, (float*)d_out);
}

// Round 13
// 595.341 us; speedup vs baseline: 1.0057x; 1.0043x over previous
//
#include <hip/hip_runtime.h>
#include <math.h>

#define VOCAB 32000
#define HDIM  512
#define NLAYERS 4
#define BATCH 32
#define TSTEPS 64
typedef unsigned long long ULL;

typedef __attribute__((ext_vector_type(8))) short bf16x8;
typedef __attribute__((ext_vector_type(4))) float f32x4;
typedef __attribute__((ext_vector_type(4))) unsigned int u32x4;

static __device__ __forceinline__ unsigned short f2b(float f) {
    union { float f; unsigned u; } v; v.f = f;
    return (unsigned short)((v.u + 0x7FFFu + ((v.u >> 16) & 1u)) >> 16);
}
static __device__ __forceinline__ float sigf(float x) { return 1.0f / (1.0f + __expf(-x)); }

// 16B AGENT-scope (coherence point = Infinity Cache) load/store.
// sc1 ONLY: bypasses non-coherent L1/L2, served by IC (~200cy).
// NOTE (round-12 post-mortem): sc0+sc1 together = SYSTEM scope -> HBM round trip
// (~900cy), which regressed k_lstm 295->386us. Do not re-add sc0.
static __device__ __forceinline__ u32x4 load16cp(const void* p) {
    u32x4 r;
    asm volatile("global_load_dwordx4 %0, %1, off sc1" : "=v"(r) : "v"(p) : "memory");
    return r;
}
static __device__ __forceinline__ void store16cp(void* p, u32x4 v) {
    asm volatile("global_store_dwordx4 %0, %1, off sc1" :: "v"(p), "v"(v) : "memory");
}
static __device__ __forceinline__ void waitvm0() {
    asm volatile("s_waitcnt vmcnt(0)" ::: "memory");
}

// packed offset of element (m,k) in a [32 rows][1024 k] bf16 operand stored in
// MFMA-fragment order: [k0=k/32][mi=m/16][lane][8]
static __device__ __forceinline__ int apack_off(int m, int k) {
    int k0 = k >> 5, mi = m >> 4;
    int lane = (m & 15) | (((k >> 3) & 3) << 4);
    return ((k0 * 2 + mi) * 64 + lane) * 8 + (k & 7);
}

// ---------------- weight prep (verified rounds 2-12) ----------------
__global__ void k_prep_w(const float* __restrict__ W_ih, const float* __restrict__ W_hh,
                         unsigned short* __restrict__ wp) {
    const int total = NLAYERS * 64 * 2 * 32 * 64 * 8;  // 8388608
    for (int idx = blockIdx.x * blockDim.x + threadIdx.x; idx < total;
         idx += gridDim.x * blockDim.x) {
        int sub = idx & 7, lane = (idx >> 3) & 63, k0 = (idx >> 9) & 31;
        int ni = (idx >> 14) & 1, bi = (idx >> 15) & 63, l = idx >> 21;
        int r = ni * 16 + (lane & 15);
        int k = k0 * 32 + ((lane >> 4) << 3) + sub;
        int j = (r & 3) * 512 + bi * 8 + (r >> 2);
        float v = (k < 512) ? W_ih[((size_t)l * 2048 + j) * 512 + k]
                            : W_hh[((size_t)l * 2048 + j) * 512 + (k - 512)];
        wp[idx] = f2b(v);
    }
}

__global__ void k_prep_bias(const float* __restrict__ b_ih, const float* __restrict__ b_hh,
                            float* __restrict__ bs) {
    int idx = blockIdx.x * blockDim.x + threadIdx.x;
    if (idx < NLAYERS * 64 * 32) {
        int r = idx & 31, bi = (idx >> 5) & 63, l = idx >> 11;
        int j = (r & 3) * 512 + bi * 8 + (r >> 2);
        bs[idx] = b_ih[l * 2048 + j] + b_hh[l * 2048 + j];
    }
}

// ---------------- W_cls -> bf16, MFMA-fragment packed (verified round 7) ----------------
__global__ void k_prep_wcls(const float* __restrict__ W_cls, unsigned short* __restrict__ wp) {
    int idx8 = blockIdx.x * blockDim.x + threadIdx.x;   // 2048000 chunks
    int lane = idx8 & 63, k0 = (idx8 >> 6) & 15, ni = (idx8 >> 10) & 1;
    int w = (idx8 >> 11) & 3, vt = idx8 >> 13;
    int v = vt * 128 + w * 32 + ni * 16 + (lane & 15);
    int kb = k0 * 32 + ((lane >> 4) << 3);
    const float* src = W_cls + (size_t)v * 512 + kb;
    float4 f0 = *(const float4*)(src);
    float4 f1 = *(const float4*)(src + 4);
    bf16x8 u;
    u[0] = (short)f2b(f0.x); u[1] = (short)f2b(f0.y);
    u[2] = (short)f2b(f0.z); u[3] = (short)f2b(f0.w);
    u[4] = (short)f2b(f1.x); u[5] = (short)f2b(f1.y);
    u[6] = (short)f2b(f1.z); u[7] = (short)f2b(f1.w);
    *(bf16x8*)(wp + (size_t)idx8 * 8) = u;
}

__global__ void k_embed(const float* __restrict__ emb, const int* __restrict__ dec,
                        float* __restrict__ seqF, unsigned short* __restrict__ seqBp) {
    int t = blockIdx.x;
    for (int i = threadIdx.x; i < BATCH * HDIM; i += blockDim.x) {
        int b = i >> 9, e = i & 511;
        int tok = dec[b * TSTEPS + t];
        float v = emb[(size_t)tok * HDIM + e];
        seqF[((size_t)t * BATCH + b) * HDIM + e] = v;
        seqBp[(size_t)t * 16384 + apack_off(b, e)] = f2b(v);
    }
}

__global__ void k_inith(const float* __restrict__ h0, unsigned short* __restrict__ apack) {
    int idx = blockIdx.x * blockDim.x + threadIdx.x;   // 65536
    int l = idx >> 14, b = (idx >> 9) & 31, d = idx & 511;
    apack[(size_t)(l * 2) * 32768 + apack_off(b, 512 + d)] =
        f2b(h0[((size_t)l * BATCH + b) * HDIM + d]);
}

// ---------------- persistent LSTM: flag pipeline (agent-scope, decongested) ----------------
// 256 blocks (layer l = blk>>6, slice bi = blk&63) x 256 threads.
// Flags packed contiguous; wave 0 polls all three conditions. Staging/exports use
// 16B sc1 (agent/IC) ops. Residual outF block-major for contiguous 1KB store/load.
__global__ __launch_bounds__(256, 1) void k_lstm(
    unsigned short* apack,                    // [4][2][32768] bf16 fragment-packed [inp|h]
    const unsigned short* __restrict__ wpack,
    const float* __restrict__ bsum,
    const unsigned short* __restrict__ seqBp, // [64][16384] packed emb (read-only, cached)
    const float* __restrict__ seqF,           // [64][32][512] fp32 emb (read-only, cached)
    float* outF,                              // [8 keys][64 bi][256] fp32 residual exchange
    unsigned short* __restrict__ seqOut,      // [32][16][4][64][8] final layer out, packed
    const float* __restrict__ c0,
    float* __restrict__ outHT, float* __restrict__ outCT,
    unsigned* flags) {                        // [4][64] u32, contiguous
    const int l = blockIdx.x >> 6, bi = blockIdx.x & 63;
    const int wave = threadIdx.x >> 6, lane = threadIdx.x & 63;
    const int mi = wave >> 1, ni = wave & 1;
    const int cb = threadIdx.x >> 3, dsl = threadIdx.x & 7;
    const int d = bi * 8 + dsl;

    __shared__ __align__(16) short sW[32768];    // 64 KB W slice
    __shared__ __align__(16) short sA[32768];    // 64 KB A staging
    __shared__ __align__(16) float sG[1024];     //  4 KB gates
    __shared__ __align__(16) short sHexH[256];   // h export repack (32b x 8d)
    __shared__ __align__(16) short sHexO[256];   // o export repack

    {   // stationary W slice -> LDS (cached reads, once)
        const unsigned short* wp = wpack + (size_t)blockIdx.x * 32768;
        #pragma unroll
        for (int i = 0; i < 16; ++i) {
            int off = (i * 256 + threadIdx.x) * 8;
            *(bf16x8*)(sW + off) = *(const bf16x8*)(wp + off);
        }
    }
    float4 bias = *(const float4*)(bsum + blockIdx.x * 32 + dsl * 4);
    float c = c0[((size_t)l * BATCH + cb) * HDIM + d];

    unsigned short* A0 = apack + (size_t)(l * 2 + 0) * 32768;
    unsigned short* A1 = apack + (size_t)(l * 2 + 1) * 32768;

    for (int t = 0; t < TSTEPS; ++t) {
        // ---- layer 0: prestage static emb inp-half (no flag dependency) ----
        if (l == 0) {
            const u32x4* sp = (const u32x4*)(seqBp + (size_t)t * 16384);
            u32x4* dA = (u32x4*)sA;
            #pragma unroll
            for (int i = 0; i < 8; ++i)
                dA[i * 256 + threadIdx.x] = sp[i * 256 + threadIdx.x];
        }

        // ---- flow control: wave 0 polls all 3 conditions on packed flags ----
        if (threadIdx.x < 64) {
            unsigned n0 = (unsigned)t;
            unsigned n1 = (unsigned)(t + 1);
            unsigned n2 = (unsigned)(t > 0 ? t - 1 : 0);
            const unsigned* f0 = flags + l * 64 + lane;
            for (;;) {
                unsigned v0 = __hip_atomic_load(f0, __ATOMIC_RELAXED, __HIP_MEMORY_SCOPE_AGENT);
                unsigned v1 = (l > 0) ? __hip_atomic_load(f0 - 64, __ATOMIC_RELAXED,
                                                          __HIP_MEMORY_SCOPE_AGENT) : 0xFFFFFFFFu;
                unsigned v2 = (l < 3) ? __hip_atomic_load(f0 + 64, __ATOMIC_RELAXED,
                                                          __HIP_MEMORY_SCOPE_AGENT) : 0xFFFFFFFFu;
                if (v0 >= n0 && v1 >= n1 && v2 >= n2) break;
                __builtin_amdgcn_s_sleep(1);
            }
        }
        __syncthreads();

        // ---- residual input (block-major outF: contiguous 1KB) ----
        float inpf;
        if (l == 0) inpf = seqF[((size_t)t * BATCH + cb) * HDIM + d];
        else inpf = __hip_atomic_load(&outF[((size_t)(l * 2 + (t & 1)) * 64 + bi) * 256 + threadIdx.x],
                                      __ATOMIC_RELAXED, __HIP_MEMORY_SCOPE_AGENT);

        // ---- stage A(l, t&1) -> LDS via 16B agent-scope loads ----
        const unsigned short* Ab = (t & 1) ? A1 : A0;
        {
            u32x4* dA = (u32x4*)sA;
            if (l == 0) {
                u32x4 tmp[8];
                #pragma unroll
                for (int i = 0; i < 8; ++i)
                    tmp[i] = load16cp((const char*)Ab + ((8 + i) * 256 + threadIdx.x) * 16);
                waitvm0();
                #pragma unroll
                for (int i = 0; i < 8; ++i)
                    dA[(8 + i) * 256 + threadIdx.x] = tmp[i];
            } else {
                u32x4 tmp[16];
                #pragma unroll
                for (int i = 0; i < 16; ++i)
                    tmp[i] = load16cp((const char*)Ab + (i * 256 + threadIdx.x) * 16);
                waitvm0();
                #pragma unroll
                for (int i = 0; i < 16; ++i)
                    dA[i * 256 + threadIdx.x] = tmp[i];
            }
        }
        __syncthreads();

        // ---- gates = A @ Wslice^T (each wave one 16x16 tile, K=1024) ----
        f32x4 acc = {0.f, 0.f, 0.f, 0.f};
        const short* abase = sA + mi * 512 + lane * 8;
        const short* wbase = sW + ni * 16384 + lane * 8;
        #pragma unroll
        for (int k0 = 0; k0 < 32; ++k0)
            acc = __builtin_amdgcn_mfma_f32_16x16x32_bf16(
                *(const bf16x8*)(abase + k0 * 1024),
                *(const bf16x8*)(wbase + k0 * 512), acc, 0, 0, 0);

        int gb = mi * 16 + (lane >> 4) * 4;
        int gr = ni * 16 + (lane & 15);
        #pragma unroll
        for (int r = 0; r < 4; ++r) sG[(gb + r) * 32 + gr] = acc[r];
        __syncthreads();

        // ---- cell update (thread owns (cb, d)) ----
        float4 g4 = *(const float4*)(sG + cb * 32 + dsl * 4);
        float gi = g4.x + bias.x, gf = g4.y + bias.y;
        float gg = g4.z + bias.z, go = g4.w + bias.w;
        float ci = sigf(gf) * c + sigf(gi) * tanhf(gg);
        float hi = sigf(go) * tanhf(ci);
        c = ci;
        float o = hi + inpf;

        sHexH[threadIdx.x] = f2b(hi);
        sHexO[threadIdx.x] = f2b(o);
        if (l < 3)    // block-major residual: contiguous 1KB agent-scope store
            __hip_atomic_store(&outF[((size_t)((l + 1) * 2 + (t & 1)) * 64 + bi) * 256 + threadIdx.x],
                               o, __ATOMIC_RELAXED, __HIP_MEMORY_SCOPE_AGENT);
        if (t == TSTEPS - 1) {
            outHT[((size_t)l * BATCH + cb) * HDIM + d] = hi;
            outCT[((size_t)l * BATCH + cb) * HDIM + d] = ci;
        }
        __syncthreads();

        // ---- export: 16B sc1 stores (layouts verified round 7/12) ----
        unsigned short* An = ((t + 1) & 1) ? A1 : A0;
        int tid = threadIdx.x;
        if (tid < 32) {
            int X = (tid & 15) | ((bi & 3) << 4);
            int chunk = (16 + (bi >> 2)) * 2 + (tid >> 4);
            store16cp((char*)An + chunk * 1024 + X * 16, ((const u32x4*)sHexH)[tid]);
        } else if (tid >= 64 && tid < 96) {
            int t2 = tid - 64;
            int X = (t2 & 15) | ((bi & 3) << 4);
            if (l < 3) {
                unsigned short* Anx = apack + (size_t)((l + 1) * 2 + (t & 1)) * 32768;
                int chunk = (bi >> 2) * 2 + (t2 >> 4);
                store16cp((char*)Anx + chunk * 1024 + X * 16, ((const u32x4*)sHexO)[t2]);
            } else {
                // fragment-packed classifier A-operand (plain store; kernel-end flush)
                int idx16 = ((t2 * 16 + (bi >> 2)) * 4 + (t >> 4)) * 64 +
                            ((t & 15) | ((bi & 3) << 4));
                ((u32x4*)seqOut)[idx16] = ((const u32x4*)sHexO)[t2];
            }
        }

        // own stores ack'd at coherence point, then publish flag = t+1
        waitvm0();
        __syncthreads();
        if (threadIdx.x == 0)
            __hip_atomic_store(&flags[l * 64 + bi], (unsigned)(t + 1),
                               __ATOMIC_RELAXED, __HIP_MEMORY_SCOPE_AGENT);
    }
}

// ---------------- fused classifier + log_softmax over T, packed operands (verified r7) ----
__global__ __launch_bounds__(256) void k_cls(
    const unsigned short* __restrict__ Ap,   // [32][16][4][64][8] packed seq
    const unsigned short* __restrict__ Wp,   // [250][4][2][16][64][8] packed W_cls
    float* __restrict__ out) {               // [B][T][V]
    int b = blockIdx.x & 31;
    int vt = blockIdx.x >> 5;
    int wave = threadIdx.x >> 6;
    int lane = threadIdx.x & 63;

    __shared__ float sL[64 * 132];   // padded stride 132 (33 KB)

    const unsigned short* abase = Ap + (size_t)b * 32768 + lane * 8;
    const unsigned short* wbase = Wp + (size_t)(vt * 4 + wave) * 16384 + lane * 8;

    f32x4 acc[4][2];
    #pragma unroll
    for (int i = 0; i < 4; ++i)
        #pragma unroll
        for (int j = 0; j < 2; ++j) acc[i][j] = (f32x4)(0.0f);

    #pragma unroll 4
    for (int k0 = 0; k0 < 16; ++k0) {
        bf16x8 a[4], bb[2];
        #pragma unroll
        for (int mi = 0; mi < 4; ++mi)
            a[mi] = *(const bf16x8*)(abase + (k0 * 4 + mi) * 512);
        #pragma unroll
        for (int ni = 0; ni < 2; ++ni)
            bb[ni] = *(const bf16x8*)(wbase + ni * 8192 + k0 * 512);
        #pragma unroll
        for (int mi = 0; mi < 4; ++mi)
            #pragma unroll
            for (int ni = 0; ni < 2; ++ni)
                acc[mi][ni] = __builtin_amdgcn_mfma_f32_16x16x32_bf16(a[mi], bb[ni], acc[mi][ni], 0, 0, 0);
    }

    #pragma unroll
    for (int ni = 0; ni < 2; ++ni) {
        float m = -1e30f;
        #pragma unroll
        for (int mi = 0; mi < 4; ++mi)
            #pragma unroll
            for (int r = 0; r < 4; ++r) m = fmaxf(m, acc[mi][ni][r]);
        m = fmaxf(m, __shfl_xor(m, 16));
        m = fmaxf(m, __shfl_xor(m, 32));
        float s = 0.f;
        #pragma unroll
        for (int mi = 0; mi < 4; ++mi)
            #pragma unroll
            for (int r = 0; r < 4; ++r) s += expf(acc[mi][ni][r] - m);
        s += __shfl_xor(s, 16);
        s += __shfl_xor(s, 32);
        float logZ = m + logf(s);
        int col = wave * 32 + ni * 16 + (lane & 15);
        #pragma unroll
        for (int mi = 0; mi < 4; ++mi) {
            #pragma unroll
            for (int r = 0; r < 4; ++r) {
                int row = mi * 16 + (lane >> 4) * 4 + r;
                sL[row * 132 + col] = acc[mi][ni][r] - logZ;
            }
        }
    }
    __syncthreads();

    float* obase = out + (size_t)b * TSTEPS * VOCAB + vt * 128;
    #pragma unroll
    for (int it = 0; it < 8; ++it) {
        int idx = it * 256 + threadIdx.x;
        int row = idx >> 5, c4 = (idx & 31) * 4;
        float4 val = *(const float4*)(sL + row * 132 + c4);
        *(float4*)(obase + (size_t)row * VOCAB + c4) = val;
    }
}

extern "C" void kernel_launch(void* const* d_in, const int* in_sizes, int n_in,
                              void* d_out, int out_size, void* d_ws, size_t ws_size,
                              hipStream_t stream) {
    const int*   dec   = (const int*)d_in[1];
    const float* h0    = (const float*)d_in[2];
    const float* c0    = (const float*)d_in[3];
    const float* emb   = (const float*)d_in[4];
    const float* W_ih  = (const float*)d_in[5];
    const float* W_hh  = (const float*)d_in[6];
    const float* b_ih  = (const float*)d_in[7];
    const float* b_hh  = (const float*)d_in[8];
    const float* W_cls = (const float*)d_in[9];

    const int LBH = NLAYERS * BATCH * HDIM;           // 65536
    const size_t BTV = (size_t)BATCH * TSTEPS * VOCAB;

    char* ws = (char*)d_ws;
    size_t off = 0;
    auto alloc = [&](size_t bytes) -> void* {
        void* p = ws + off;
        off = (off + bytes + 255) & ~(size_t)255;
        return p;
    };
    unsigned short* wpack  = (unsigned short*)alloc((size_t)NLAYERS * 64 * 2 * 32 * 64 * 8 * 2);
    float*          bsum   = (float*)alloc((size_t)NLAYERS * 64 * 32 * 4);
    unsigned short* wpackC = (unsigned short*)alloc((size_t)VOCAB * HDIM * 2);
    float*          seqF   = (float*)alloc((size_t)TSTEPS * BATCH * HDIM * 4);
    unsigned short* seqBp  = (unsigned short*)alloc((size_t)TSTEPS * 16384 * 2);
    unsigned short* apack  = (unsigned short*)alloc((size_t)NLAYERS * 2 * 32768 * 2);
    float*          outF   = (float*)alloc((size_t)8 * 64 * 256 * 4);
    unsigned short* apackC = (unsigned short*)alloc((size_t)TSTEPS * BATCH * HDIM * 2);
    unsigned*       flags  = (unsigned*)alloc(1024);

    k_prep_w<<<4096, 256, 0, stream>>>(W_ih, W_hh, wpack);
    k_prep_bias<<<32, 256, 0, stream>>>(b_ih, b_hh, bsum);
    k_prep_wcls<<<8000, 256, 0, stream>>>(W_cls, wpackC);
    k_embed<<<TSTEPS, 256, 0, stream>>>(emb, dec, seqF, seqBp);
    k_inith<<<256, 256, 0, stream>>>(h0, apack);
    hipMemsetAsync(flags, 0, 1024, stream);

    k_lstm<<<256, 256, 0, stream>>>(apack, wpack, bsum, seqBp, seqF, outF, apackC,
                                    c0,
                                    (float*)d_out + BTV,
                                    (float*)d_out + BTV + LBH,
                                    flags);

    k_cls<<<250 * 32, 256, 0, stream>>>(apackC, wpackC, (float*)d_out);
}

// Round 14
// 489.711 us; speedup vs baseline: 1.2226x; 1.2157x over previous
//
#include <hip/hip_runtime.h>
#include <math.h>

#define VOCAB 32000
#define HDIM  512
#define NLAYERS 4
#define BATCH 32
#define TSTEPS 64
typedef unsigned long long ULL;

typedef __attribute__((ext_vector_type(8))) short bf16x8;
typedef __attribute__((ext_vector_type(4))) float f32x4;
typedef __attribute__((ext_vector_type(4))) unsigned int u32x4;

static __device__ __forceinline__ unsigned short f2b(float f) {
    union { float f; unsigned u; } v; v.f = f;
    return (unsigned short)((v.u + 0x7FFFu + ((v.u >> 16) & 1u)) >> 16);
}
static __device__ __forceinline__ float sigf(float x) { return 1.0f / (1.0f + __expf(-x)); }

// packed offset of element (m,k) in a [32 rows][1024 k] bf16 operand stored in
// MFMA-fragment order: [k0=k/32][mi=m/16][lane][8]
static __device__ __forceinline__ int apack_off(int m, int k) {
    int k0 = k >> 5, mi = m >> 4;
    int lane = (m & 15) | (((k >> 3) & 3) << 4);
    return ((k0 * 2 + mi) * 64 + lane) * 8 + (k & 7);
}

// ---------------- weight prep (verified rounds 2-13) ----------------
__global__ void k_prep_w(const float* __restrict__ W_ih, const float* __restrict__ W_hh,
                         unsigned short* __restrict__ wp) {
    const int total = NLAYERS * 64 * 2 * 32 * 64 * 8;  // 8388608
    for (int idx = blockIdx.x * blockDim.x + threadIdx.x; idx < total;
         idx += gridDim.x * blockDim.x) {
        int sub = idx & 7, lane = (idx >> 3) & 63, k0 = (idx >> 9) & 31;
        int ni = (idx >> 14) & 1, bi = (idx >> 15) & 63, l = idx >> 21;
        int r = ni * 16 + (lane & 15);
        int k = k0 * 32 + ((lane >> 4) << 3) + sub;
        int j = (r & 3) * 512 + bi * 8 + (r >> 2);
        float v = (k < 512) ? W_ih[((size_t)l * 2048 + j) * 512 + k]
                            : W_hh[((size_t)l * 2048 + j) * 512 + (k - 512)];
        wp[idx] = f2b(v);
    }
}

__global__ void k_prep_bias(const float* __restrict__ b_ih, const float* __restrict__ b_hh,
                            float* __restrict__ bs) {
    int idx = blockIdx.x * blockDim.x + threadIdx.x;
    if (idx < NLAYERS * 64 * 32) {
        int r = idx & 31, bi = (idx >> 5) & 63, l = idx >> 11;
        int j = (r & 3) * 512 + bi * 8 + (r >> 2);
        bs[idx] = b_ih[l * 2048 + j] + b_hh[l * 2048 + j];
    }
}

// ---------------- W_cls -> bf16, MFMA-fragment packed (verified round 7) ----------------
__global__ void k_prep_wcls(const float* __restrict__ W_cls, unsigned short* __restrict__ wp) {
    int idx8 = blockIdx.x * blockDim.x + threadIdx.x;   // 2048000 chunks
    int lane = idx8 & 63, k0 = (idx8 >> 6) & 15, ni = (idx8 >> 10) & 1;
    int w = (idx8 >> 11) & 3, vt = idx8 >> 13;
    int v = vt * 128 + w * 32 + ni * 16 + (lane & 15);
    int kb = k0 * 32 + ((lane >> 4) << 3);
    const float* src = W_cls + (size_t)v * 512 + kb;
    float4 f0 = *(const float4*)(src);
    float4 f1 = *(const float4*)(src + 4);
    bf16x8 u;
    u[0] = (short)f2b(f0.x); u[1] = (short)f2b(f0.y);
    u[2] = (short)f2b(f0.z); u[3] = (short)f2b(f0.w);
    u[4] = (short)f2b(f1.x); u[5] = (short)f2b(f1.y);
    u[6] = (short)f2b(f1.z); u[7] = (short)f2b(f1.w);
    *(bf16x8*)(wp + (size_t)idx8 * 8) = u;
}

__global__ void k_embed(const float* __restrict__ emb, const int* __restrict__ dec,
                        float* __restrict__ seqF, unsigned short* __restrict__ seqBp) {
    int t = blockIdx.x;
    for (int i = threadIdx.x; i < BATCH * HDIM; i += blockDim.x) {
        int b = i >> 9, e = i & 511;
        int tok = dec[b * TSTEPS + t];
        float v = emb[(size_t)tok * HDIM + e];
        seqF[((size_t)t * BATCH + b) * HDIM + e] = v;
        seqBp[(size_t)t * 16384 + apack_off(b, e)] = f2b(v);
    }
}

__global__ void k_inith(const float* __restrict__ h0, unsigned short* __restrict__ apack) {
    int idx = blockIdx.x * blockDim.x + threadIdx.x;   // 65536
    int l = idx >> 14, b = (idx >> 9) & 31, d = idx & 511;
    apack[(size_t)(l * 2) * 32768 + apack_off(b, 512 + d)] =
        f2b(h0[((size_t)l * BATCH + b) * HDIM + d]);
}

// ---------------- persistent LSTM: fence-free flag pipeline ----------------
// EXACT round-7 protocol (measured 295us): 64B-stride flags, 3-wave per-lane polls,
// 8B __hip_atomic staging/exports, scattered-4B outF residual.
// Round 12/13 lesson: bundled "optimizations" (16B asm + vmcnt(0) drain, contiguous
// flags + fused poll, block-major outF) REGRESSED to ~390us. Reverted wholesale.
// Single addition vs r7: layer-0 prestages its (read-only) emb inp-half BEFORE the
// poll — removes 8 cached loads from the pipeline-head critical path. Race-free:
// sA is only read in the MFMA phase, which completes before the end-of-step barrier.
__global__ __launch_bounds__(256, 1) void k_lstm(
    unsigned short* apack,                    // [4][2][32768] bf16 fragment-packed [inp|h]
    const unsigned short* __restrict__ wpack,
    const float* __restrict__ bsum,
    const unsigned short* __restrict__ seqBp, // [64][16384] packed emb (read-only, cached)
    const float* __restrict__ seqF,           // [64][32][512] fp32 emb (residual for l=0)
    float* outF,                              // [4][2][32][512] fp32 residual exchange
    unsigned short* __restrict__ seqOut,      // [32][16][4][64][8] final layer out, packed
    const float* __restrict__ c0,
    float* __restrict__ outHT, float* __restrict__ outCT,
    unsigned* flags) {                        // [4][64] flags, 64B stride
    const int l = blockIdx.x >> 6, bi = blockIdx.x & 63;
    const int wave = threadIdx.x >> 6, lane = threadIdx.x & 63;
    const int mi = wave >> 1, ni = wave & 1;
    const int cb = threadIdx.x >> 3, dsl = threadIdx.x & 7;
    const int d = bi * 8 + dsl;

    __shared__ __align__(16) short sW[32768];    // 64 KB W slice
    __shared__ __align__(16) short sA[32768];    // 64 KB A staging
    __shared__ __align__(16) float sG[1024];     //  4 KB gates
    __shared__ __align__(16) short sHexH[512];   //  1 KB h export repack
    __shared__ __align__(16) short sHexO[512];   //  1 KB o export repack

    {   // stationary W slice -> LDS (cached reads, once)
        const unsigned short* wp = wpack + (size_t)blockIdx.x * 32768;
        #pragma unroll
        for (int i = 0; i < 16; ++i) {
            int off = (i * 256 + threadIdx.x) * 8;
            *(bf16x8*)(sW + off) = *(const bf16x8*)(wp + off);
        }
    }
    float4 bias = *(const float4*)(bsum + blockIdx.x * 32 + dsl * 4);
    float c = c0[((size_t)l * BATCH + cb) * HDIM + d];

    unsigned short* A0 = apack + (size_t)(l * 2 + 0) * 32768;
    unsigned short* A1 = apack + (size_t)(l * 2 + 1) * 32768;

    for (int t = 0; t < TSTEPS; ++t) {
        // ---- layer 0: prestage static emb inp-half (no flag dependency) ----
        if (l == 0) {
            const unsigned short* sp = seqBp + (size_t)t * 16384;
            #pragma unroll
            for (int i = 0; i < 8; ++i) {
                int off = (i * 256 + threadIdx.x) * 8;
                *(bf16x8*)(sA + off) = *(const bf16x8*)(sp + off);
            }
        }

        // ---- flow control: 3 waves spin per-lane on per-producer flags (r7-exact) ----
        if (wave == 0 && t > 0) {                    // own layer finished step t-1
            const unsigned* fp = flags + (l * 64 + lane) * 16;
            while (__hip_atomic_load(fp, __ATOMIC_RELAXED, __HIP_MEMORY_SCOPE_AGENT)
                   < (unsigned)t)
                __builtin_amdgcn_s_sleep(1);
        }
        if (wave == 1 && l > 0) {                    // upstream finished step t
            const unsigned* fp = flags + ((l - 1) * 64 + lane) * 16;
            while (__hip_atomic_load(fp, __ATOMIC_RELAXED, __HIP_MEMORY_SCOPE_AGENT)
                   < (unsigned)(t + 1))
                __builtin_amdgcn_s_sleep(1);
        }
        if (wave == 2 && l < 3 && t > 0) {           // downstream consumed parity buffer
            const unsigned* fp = flags + ((l + 1) * 64 + lane) * 16;
            while (__hip_atomic_load(fp, __ATOMIC_RELAXED, __HIP_MEMORY_SCOPE_AGENT)
                   < (unsigned)(t - 1))
                __builtin_amdgcn_s_sleep(1);
        }
        __syncthreads();

        // ---- residual input: fp32, issued early to hide latency ----
        float inpf;
        if (l == 0) inpf = seqF[((size_t)t * BATCH + cb) * HDIM + d];
        else inpf = __hip_atomic_load(&outF[(size_t)((l * 2 + (t & 1)) * BATCH + cb) * HDIM + d],
                                      __ATOMIC_RELAXED, __HIP_MEMORY_SCOPE_AGENT);

        // ---- stage A(l, t&1) -> LDS via 8B coherence-point loads (batched, r7-exact) ----
        const unsigned short* Ab = (t & 1) ? A1 : A0;
        const ULL* Abu = (const ULL*)Ab;
        ULL* sAu = (ULL*)sA;
        if (l == 0) {
            ULL tmp[16];
            #pragma unroll
            for (int i = 0; i < 16; ++i)           // h half only (inp prestaged)
                tmp[i] = __hip_atomic_load(&Abu[(16 + i) * 256 + threadIdx.x],
                                           __ATOMIC_RELAXED, __HIP_MEMORY_SCOPE_AGENT);
            #pragma unroll
            for (int i = 0; i < 16; ++i)
                sAu[(16 + i) * 256 + threadIdx.x] = tmp[i];
        } else {
            ULL tmp[32];
            #pragma unroll
            for (int i = 0; i < 32; ++i)
                tmp[i] = __hip_atomic_load(&Abu[i * 256 + threadIdx.x],
                                           __ATOMIC_RELAXED, __HIP_MEMORY_SCOPE_AGENT);
            #pragma unroll
            for (int i = 0; i < 32; ++i)
                sAu[i * 256 + threadIdx.x] = tmp[i];
        }
        __syncthreads();

        // ---- gates = A @ Wslice^T (each wave one 16x16 tile, K=1024) ----
        f32x4 acc = {0.f, 0.f, 0.f, 0.f};
        const short* abase = sA + mi * 512 + lane * 8;
        const short* wbase = sW + ni * 16384 + lane * 8;
        #pragma unroll
        for (int k0 = 0; k0 < 32; ++k0)
            acc = __builtin_amdgcn_mfma_f32_16x16x32_bf16(
                *(const bf16x8*)(abase + k0 * 1024),
                *(const bf16x8*)(wbase + k0 * 512), acc, 0, 0, 0);

        int gb = mi * 16 + (lane >> 4) * 4;
        int gr = ni * 16 + (lane & 15);
        #pragma unroll
        for (int r = 0; r < 4; ++r) sG[(gb + r) * 32 + gr] = acc[r];
        __syncthreads();

        // ---- cell update (thread owns (cb, d)) ----
        float4 g4 = *(const float4*)(sG + cb * 32 + dsl * 4);
        float gi = g4.x + bias.x, gf = g4.y + bias.y;
        float gg = g4.z + bias.z, go = g4.w + bias.w;
        float ci = sigf(gf) * c + sigf(gi) * tanhf(gg);
        float hi = sigf(go) * tanhf(ci);
        c = ci;
        float o = hi + inpf;

        sHexH[threadIdx.x] = f2b(hi);
        sHexO[threadIdx.x] = f2b(o);
        if (l < 3)    // fp32 residual: agent-scope store straight to coherence point
            __hip_atomic_store(&outF[(size_t)(((l + 1) * 2 + (t & 1)) * BATCH + cb) * HDIM + d],
                               o, __ATOMIC_RELAXED, __HIP_MEMORY_SCOPE_AGENT);
        if (t == TSTEPS - 1) {
            outHT[((size_t)l * BATCH + cb) * HDIM + d] = hi;
            outCT[((size_t)l * BATCH + cb) * HDIM + d] = ci;
        }
        __syncthreads();

        // ---- export: coalesced 8B agent-scope stores (r7-exact layouts) ----
        unsigned short* An = ((t + 1) & 1) ? A1 : A0;
        int i = threadIdx.x & 63, cbe = i >> 1, jh = i & 1;
        int lanecode = ((cbe & 15) | ((bi & 3) << 4)) * 2 + jh;
        if (threadIdx.x < 64) {
            int hoff = ((16 + (bi >> 2)) * 2 + (cbe >> 4)) * 128 + lanecode;
            __hip_atomic_store(&((ULL*)An)[hoff], ((const ULL*)sHexH)[i],
                               __ATOMIC_RELAXED, __HIP_MEMORY_SCOPE_AGENT);
        } else if (threadIdx.x < 128) {
            if (l < 3) {
                unsigned short* Anx = apack + (size_t)((l + 1) * 2 + (t & 1)) * 32768;
                int ooff = ((bi >> 2) * 2 + (cbe >> 4)) * 128 + lanecode;
                __hip_atomic_store(&((ULL*)Anx)[ooff], ((const ULL*)sHexO)[i],
                                   __ATOMIC_RELAXED, __HIP_MEMORY_SCOPE_AGENT);
            } else {
                // fragment-packed classifier A-operand (plain store; kernel-end flush)
                int ulidx = ((((cbe * 16 + (bi >> 2)) * 4 + (t >> 4)) * 64 +
                             ((t & 15) | ((bi & 3) << 4))) * 2) + jh;
                ((ULL*)seqOut)[ulidx] = ((const ULL*)sHexO)[i];
            }
        }

        // own stores ack'd at coherence point, then publish flag = t+1
        asm volatile("s_waitcnt vmcnt(0)" ::: "memory");
        __syncthreads();
        if (threadIdx.x == 0)
            __hip_atomic_store(&flags[(l * 64 + bi) * 16], (unsigned)(t + 1),
                               __ATOMIC_RELAXED, __HIP_MEMORY_SCOPE_AGENT);
    }
}

// ---------------- fused classifier + log_softmax over T, packed operands (verified r7) ----
__global__ __launch_bounds__(256) void k_cls(
    const unsigned short* __restrict__ Ap,   // [32][16][4][64][8] packed seq
    const unsigned short* __restrict__ Wp,   // [250][4][2][16][64][8] packed W_cls
    float* __restrict__ out) {               // [B][T][V]
    int b = blockIdx.x & 31;
    int vt = blockIdx.x >> 5;
    int wave = threadIdx.x >> 6;
    int lane = threadIdx.x & 63;

    __shared__ float sL[64 * 132];   // padded stride 132 (33 KB)

    const unsigned short* abase = Ap + (size_t)b * 32768 + lane * 8;
    const unsigned short* wbase = Wp + (size_t)(vt * 4 + wave) * 16384 + lane * 8;

    f32x4 acc[4][2];
    #pragma unroll
    for (int i = 0; i < 4; ++i)
        #pragma unroll
        for (int j = 0; j < 2; ++j) acc[i][j] = (f32x4)(0.0f);

    #pragma unroll 4
    for (int k0 = 0; k0 < 16; ++k0) {
        bf16x8 a[4], bb[2];
        #pragma unroll
        for (int mi = 0; mi < 4; ++mi)
            a[mi] = *(const bf16x8*)(abase + (k0 * 4 + mi) * 512);
        #pragma unroll
        for (int ni = 0; ni < 2; ++ni)
            bb[ni] = *(const bf16x8*)(wbase + ni * 8192 + k0 * 512);
        #pragma unroll
        for (int mi = 0; mi < 4; ++mi)
            #pragma unroll
            for (int ni = 0; ni < 2; ++ni)
                acc[mi][ni] = __builtin_amdgcn_mfma_f32_16x16x32_bf16(a[mi], bb[ni], acc[mi][ni], 0, 0, 0);
    }

    #pragma unroll
    for (int ni = 0; ni < 2; ++ni) {
        float m = -1e30f;
        #pragma unroll
        for (int mi = 0; mi < 4; ++mi)
            #pragma unroll
            for (int r = 0; r < 4; ++r) m = fmaxf(m, acc[mi][ni][r]);
        m = fmaxf(m, __shfl_xor(m, 16));
        m = fmaxf(m, __shfl_xor(m, 32));
        float s = 0.f;
        #pragma unroll
        for (int mi = 0; mi < 4; ++mi)
            #pragma unroll
            for (int r = 0; r < 4; ++r) s += expf(acc[mi][ni][r] - m);
        s += __shfl_xor(s, 16);
        s += __shfl_xor(s, 32);
        float logZ = m + logf(s);
        int col = wave * 32 + ni * 16 + (lane & 15);
        #pragma unroll
        for (int mi = 0; mi < 4; ++mi) {
            #pragma unroll
            for (int r = 0; r < 4; ++r) {
                int row = mi * 16 + (lane >> 4) * 4 + r;
                sL[row * 132 + col] = acc[mi][ni][r] - logZ;
            }
        }
    }
    __syncthreads();

    float* obase = out + (size_t)b * TSTEPS * VOCAB + vt * 128;
    #pragma unroll
    for (int it = 0; it < 8; ++it) {
        int idx = it * 256 + threadIdx.x;
        int row = idx >> 5, c4 = (idx & 31) * 4;
        float4 val = *(const float4*)(sL + row * 132 + c4);
        *(float4*)(obase + (size_t)row * VOCAB + c4) = val;
    }
}

extern "C" void kernel_launch(void* const* d_in, const int* in_sizes, int n_in,
                              void* d_out, int out_size, void* d_ws, size_t ws_size,
                              hipStream_t stream) {
    const int*   dec   = (const int*)d_in[1];
    const float* h0    = (const float*)d_in[2];
    const float* c0    = (const float*)d_in[3];
    const float* emb   = (const float*)d_in[4];
    const float* W_ih  = (const float*)d_in[5];
    const float* W_hh  = (const float*)d_in[6];
    const float* b_ih  = (const float*)d_in[7];
    const float* b_hh  = (const float*)d_in[8];
    const float* W_cls = (const float*)d_in[9];

    const int LBH = NLAYERS * BATCH * HDIM;           // 65536
    const size_t BTV = (size_t)BATCH * TSTEPS * VOCAB;

    char* ws = (char*)d_ws;
    size_t off = 0;
    auto alloc = [&](size_t bytes) -> void* {
        void* p = ws + off;
        off = (off + bytes + 255) & ~(size_t)255;
        return p;
    };
    unsigned short* wpack  = (unsigned short*)alloc((size_t)NLAYERS * 64 * 2 * 32 * 64 * 8 * 2);
    float*          bsum   = (float*)alloc((size_t)NLAYERS * 64 * 32 * 4);
    unsigned short* wpackC = (unsigned short*)alloc((size_t)VOCAB * HDIM * 2);
    float*          seqF   = (float*)alloc((size_t)TSTEPS * BATCH * HDIM * 4);
    unsigned short* seqBp  = (unsigned short*)alloc((size_t)TSTEPS * 16384 * 2);
    unsigned short* apack  = (unsigned short*)alloc((size_t)NLAYERS * 2 * 32768 * 2);
    float*          outF   = (float*)alloc((size_t)NLAYERS * 2 * BATCH * HDIM * 4);
    unsigned short* apackC = (unsigned short*)alloc((size_t)TSTEPS * BATCH * HDIM * 2);
    unsigned*       flags  = (unsigned*)alloc(16384);

    k_prep_w<<<4096, 256, 0, stream>>>(W_ih, W_hh, wpack);
    k_prep_bias<<<32, 256, 0, stream>>>(b_ih, b_hh, bsum);
    k_prep_wcls<<<8000, 256, 0, stream>>>(W_cls, wpackC);
    k_embed<<<TSTEPS, 256, 0, stream>>>(emb, dec, seqF, seqBp);
    k_inith<<<256, 256, 0, stream>>>(h0, apack);
    hipMemsetAsync(flags, 0, 16384, stream);

    k_lstm<<<256, 256, 0, stream>>>(apack, wpack, bsum, seqBp, seqF, outF, apackC,
                                    c0,
                                    (float*)d_out + BTV,
                                    (float*)d_out + BTV + LBH,
                                    flags);

    k_cls<<<250 * 32, 256, 0, stream>>>(apackC, wpackC, (float*)d_out);
}

// Round 16
// 458.357 us; speedup vs baseline: 1.3062x; 1.0684x over previous
//
#include <hip/hip_runtime.h>
#include <math.h>

#define VOCAB 32000
#define HDIM  512
#define NLAYERS 4
#define BATCH 32
#define TSTEPS 64
typedef unsigned long long ULL;

typedef __attribute__((ext_vector_type(8))) short bf16x8;
typedef __attribute__((ext_vector_type(4))) float f32x4;
typedef __attribute__((ext_vector_type(4))) unsigned int u32x4;

static __device__ __forceinline__ unsigned short f2b(float f) {
    union { float f; unsigned u; } v; v.f = f;
    return (unsigned short)((v.u + 0x7FFFu + ((v.u >> 16) & 1u)) >> 16);
}
static __device__ __forceinline__ float sigf(float x) { return 1.0f / (1.0f + __expf(-x)); }

// packed offset of element (m,k) in a [32 rows][1024 k] bf16 operand stored in
// MFMA-fragment order: [k0=k/32][mi=m/16][lane][8]
static __device__ __forceinline__ int apack_off(int m, int k) {
    int k0 = k >> 5, mi = m >> 4;
    int lane = (m & 15) | (((k >> 3) & 3) << 4);
    return ((k0 * 2 + mi) * 64 + lane) * 8 + (k & 7);
}

// ---------------- ALL preps fused into one dispatch (bodies byte-identical to the
// verified r2-r14 kernels; only the index source changed). Block ranges:
//   [0,4096)            prep_w      (grid-stride, total 8388608)
//   [4096,12096)        prep_wcls   (one chunk per thread, 2048000)
//   [12096,12160)       embed       (t = blk-12096)
//   [12160,12416)       inith       (65536 threads)
//   [12416,12448)       prep_bias   (8192 threads)
//   [12448]             flags zero  (4096 u32)
__global__ void k_prep_all(
    const float* __restrict__ W_ih, const float* __restrict__ W_hh,
    const float* __restrict__ b_ih, const float* __restrict__ b_hh,
    const float* __restrict__ W_cls, const float* __restrict__ emb,
    const int* __restrict__ dec, const float* __restrict__ h0,
    unsigned short* __restrict__ wp, float* __restrict__ bs,
    unsigned short* __restrict__ wpC, float* __restrict__ seqF,
    unsigned short* __restrict__ seqBp, unsigned short* __restrict__ apack,
    unsigned* __restrict__ flags) {
    int blk = blockIdx.x;
    if (blk < 4096) {
        const int total = NLAYERS * 64 * 2 * 32 * 64 * 8;  // 8388608
        for (int idx = blk * 256 + threadIdx.x; idx < total; idx += 4096 * 256) {
            int sub = idx & 7, lane = (idx >> 3) & 63, k0 = (idx >> 9) & 31;
            int ni = (idx >> 14) & 1, bi = (idx >> 15) & 63, l = idx >> 21;
            int r = ni * 16 + (lane & 15);
            int k = k0 * 32 + ((lane >> 4) << 3) + sub;
            int j = (r & 3) * 512 + bi * 8 + (r >> 2);
            float v = (k < 512) ? W_ih[((size_t)l * 2048 + j) * 512 + k]
                                : W_hh[((size_t)l * 2048 + j) * 512 + (k - 512)];
            wp[idx] = f2b(v);
        }
    } else if (blk < 12096) {
        int idx8 = (blk - 4096) * 256 + threadIdx.x;   // 2048000 chunks
        int lane = idx8 & 63, k0 = (idx8 >> 6) & 15, ni = (idx8 >> 10) & 1;
        int w = (idx8 >> 11) & 3, vt = idx8 >> 13;
        int v = vt * 128 + w * 32 + ni * 16 + (lane & 15);
        int kb = k0 * 32 + ((lane >> 4) << 3);
        const float* src = W_cls + (size_t)v * 512 + kb;
        float4 f0 = *(const float4*)(src);
        float4 f1 = *(const float4*)(src + 4);
        bf16x8 u;
        u[0] = (short)f2b(f0.x); u[1] = (short)f2b(f0.y);
        u[2] = (short)f2b(f0.z); u[3] = (short)f2b(f0.w);
        u[4] = (short)f2b(f1.x); u[5] = (short)f2b(f1.y);
        u[6] = (short)f2b(f1.z); u[7] = (short)f2b(f1.w);
        *(bf16x8*)(wpC + (size_t)idx8 * 8) = u;
    } else if (blk < 12160) {
        int t = blk - 12096;
        for (int i = threadIdx.x; i < BATCH * HDIM; i += blockDim.x) {
            int b = i >> 9, e = i & 511;
            int tok = dec[b * TSTEPS + t];
            float v = emb[(size_t)tok * HDIM + e];
            seqF[((size_t)t * BATCH + b) * HDIM + e] = v;
            seqBp[(size_t)t * 16384 + apack_off(b, e)] = f2b(v);
        }
    } else if (blk < 12416) {
        int idx = (blk - 12160) * 256 + threadIdx.x;   // 65536
        int l = idx >> 14, b = (idx >> 9) & 31, d = idx & 511;
        apack[(size_t)(l * 2) * 32768 + apack_off(b, 512 + d)] =
            f2b(h0[((size_t)l * BATCH + b) * HDIM + d]);
    } else if (blk < 12448) {
        int idx = (blk - 12416) * 256 + threadIdx.x;
        if (idx < NLAYERS * 64 * 32) {
            int r = idx & 31, bi = (idx >> 5) & 63, l = idx >> 11;
            int j = (r & 3) * 512 + bi * 8 + (r >> 2);
            bs[idx] = b_ih[l * 2048 + j] + b_hh[l * 2048 + j];
        }
    } else {
        for (int i = threadIdx.x; i < 4096; i += 256) flags[i] = 0;
    }
}

// ---------------- persistent LSTM: fence-free flag pipeline ----------------
// EXACT round-14 code (measured 284us). 64B-stride flags, 3-wave per-lane polls,
// 8B __hip_atomic staging/exports, layer-0 prestage of the cached emb inp-half.
// r12/13 lesson: do NOT bundle protocol tweaks (16B asm + vmcnt drain, fused poll,
// block-major outF regressed to ~390us).
__global__ __launch_bounds__(256, 1) void k_lstm(
    unsigned short* apack,                    // [4][2][32768] bf16 fragment-packed [inp|h]
    const unsigned short* __restrict__ wpack,
    const float* __restrict__ bsum,
    const unsigned short* __restrict__ seqBp, // [64][16384] packed emb (read-only, cached)
    const float* __restrict__ seqF,           // [64][32][512] fp32 emb (residual for l=0)
    float* outF,                              // [4][2][32][512] fp32 residual exchange
    unsigned short* __restrict__ seqOut,      // [32][16][4][64][8] final layer out, packed
    const float* __restrict__ c0,
    float* __restrict__ outHT, float* __restrict__ outCT,
    unsigned* flags) {                        // [4][64] flags, 64B stride
    const int l = blockIdx.x >> 6, bi = blockIdx.x & 63;
    const int wave = threadIdx.x >> 6, lane = threadIdx.x & 63;
    const int mi = wave >> 1, ni = wave & 1;
    const int cb = threadIdx.x >> 3, dsl = threadIdx.x & 7;
    const int d = bi * 8 + dsl;

    __shared__ __align__(16) short sW[32768];    // 64 KB W slice
    __shared__ __align__(16) short sA[32768];    // 64 KB A staging
    __shared__ __align__(16) float sG[1024];     //  4 KB gates
    __shared__ __align__(16) short sHexH[512];   //  1 KB h export repack
    __shared__ __align__(16) short sHexO[512];   //  1 KB o export repack

    {   // stationary W slice -> LDS (cached reads, once)
        const unsigned short* wp = wpack + (size_t)blockIdx.x * 32768;
        #pragma unroll
        for (int i = 0; i < 16; ++i) {
            int off = (i * 256 + threadIdx.x) * 8;
            *(bf16x8*)(sW + off) = *(const bf16x8*)(wp + off);
        }
    }
    float4 bias = *(const float4*)(bsum + blockIdx.x * 32 + dsl * 4);
    float c = c0[((size_t)l * BATCH + cb) * HDIM + d];

    unsigned short* A0 = apack + (size_t)(l * 2 + 0) * 32768;
    unsigned short* A1 = apack + (size_t)(l * 2 + 1) * 32768;

    for (int t = 0; t < TSTEPS; ++t) {
        // ---- layer 0: prestage static emb inp-half (no flag dependency) ----
        if (l == 0) {
            const unsigned short* sp = seqBp + (size_t)t * 16384;
            #pragma unroll
            for (int i = 0; i < 8; ++i) {
                int off = (i * 256 + threadIdx.x) * 8;
                *(bf16x8*)(sA + off) = *(const bf16x8*)(sp + off);
            }
        }

        // ---- flow control: 3 waves spin per-lane on per-producer flags ----
        if (wave == 0 && t > 0) {                    // own layer finished step t-1
            const unsigned* fp = flags + (l * 64 + lane) * 16;
            while (__hip_atomic_load(fp, __ATOMIC_RELAXED, __HIP_MEMORY_SCOPE_AGENT)
                   < (unsigned)t)
                __builtin_amdgcn_s_sleep(1);
        }
        if (wave == 1 && l > 0) {                    // upstream finished step t
            const unsigned* fp = flags + ((l - 1) * 64 + lane) * 16;
            while (__hip_atomic_load(fp, __ATOMIC_RELAXED, __HIP_MEMORY_SCOPE_AGENT)
                   < (unsigned)(t + 1))
                __builtin_amdgcn_s_sleep(1);
        }
        if (wave == 2 && l < 3 && t > 0) {           // downstream consumed parity buffer
            const unsigned* fp = flags + ((l + 1) * 64 + lane) * 16;
            while (__hip_atomic_load(fp, __ATOMIC_RELAXED, __HIP_MEMORY_SCOPE_AGENT)
                   < (unsigned)(t - 1))
                __builtin_amdgcn_s_sleep(1);
        }
        __syncthreads();

        // ---- residual input: fp32, issued early to hide latency ----
        float inpf;
        if (l == 0) inpf = seqF[((size_t)t * BATCH + cb) * HDIM + d];
        else inpf = __hip_atomic_load(&outF[(size_t)((l * 2 + (t & 1)) * BATCH + cb) * HDIM + d],
                                      __ATOMIC_RELAXED, __HIP_MEMORY_SCOPE_AGENT);

        // ---- stage A(l, t&1) -> LDS via 8B coherence-point loads (batched) ----
        const unsigned short* Ab = (t & 1) ? A1 : A0;
        const ULL* Abu = (const ULL*)Ab;
        ULL* sAu = (ULL*)sA;
        if (l == 0) {
            ULL tmp[16];
            #pragma unroll
            for (int i = 0; i < 16; ++i)           // h half only (inp prestaged)
                tmp[i] = __hip_atomic_load(&Abu[(16 + i) * 256 + threadIdx.x],
                                           __ATOMIC_RELAXED, __HIP_MEMORY_SCOPE_AGENT);
            #pragma unroll
            for (int i = 0; i < 16; ++i)
                sAu[(16 + i) * 256 + threadIdx.x] = tmp[i];
        } else {
            ULL tmp[32];
            #pragma unroll
            for (int i = 0; i < 32; ++i)
                tmp[i] = __hip_atomic_load(&Abu[i * 256 + threadIdx.x],
                                           __ATOMIC_RELAXED, __HIP_MEMORY_SCOPE_AGENT);
            #pragma unroll
            for (int i = 0; i < 32; ++i)
                sAu[i * 256 + threadIdx.x] = tmp[i];
        }
        __syncthreads();

        // ---- gates = A @ Wslice^T (each wave one 16x16 tile, K=1024) ----
        f32x4 acc = {0.f, 0.f, 0.f, 0.f};
        const short* abase = sA + mi * 512 + lane * 8;
        const short* wbase = sW + ni * 16384 + lane * 8;
        #pragma unroll
        for (int k0 = 0; k0 < 32; ++k0)
            acc = __builtin_amdgcn_mfma_f32_16x16x32_bf16(
                *(const bf16x8*)(abase + k0 * 1024),
                *(const bf16x8*)(wbase + k0 * 512), acc, 0, 0, 0);

        int gb = mi * 16 + (lane >> 4) * 4;
        int gr = ni * 16 + (lane & 15);
        #pragma unroll
        for (int r = 0; r < 4; ++r) sG[(gb + r) * 32 + gr] = acc[r];
        __syncthreads();

        // ---- cell update (thread owns (cb, d)) ----
        float4 g4 = *(const float4*)(sG + cb * 32 + dsl * 4);
        float gi = g4.x + bias.x, gf = g4.y + bias.y;
        float gg = g4.z + bias.z, go = g4.w + bias.w;
        float ci = sigf(gf) * c + sigf(gi) * tanhf(gg);
        float hi = sigf(go) * tanhf(ci);
        c = ci;
        float o = hi + inpf;

        sHexH[threadIdx.x] = f2b(hi);
        sHexO[threadIdx.x] = f2b(o);
        if (l < 3)    // fp32 residual: agent-scope store straight to coherence point
            __hip_atomic_store(&outF[(size_t)(((l + 1) * 2 + (t & 1)) * BATCH + cb) * HDIM + d],
                               o, __ATOMIC_RELAXED, __HIP_MEMORY_SCOPE_AGENT);
        if (t == TSTEPS - 1) {
            outHT[((size_t)l * BATCH + cb) * HDIM + d] = hi;
            outCT[((size_t)l * BATCH + cb) * HDIM + d] = ci;
        }
        __syncthreads();

        // ---- export: coalesced 8B agent-scope stores ----
        unsigned short* An = ((t + 1) & 1) ? A1 : A0;
        int i = threadIdx.x & 63, cbe = i >> 1, jh = i & 1;
        int lanecode = ((cbe & 15) | ((bi & 3) << 4)) * 2 + jh;
        if (threadIdx.x < 64) {
            int hoff = ((16 + (bi >> 2)) * 2 + (cbe >> 4)) * 128 + lanecode;
            __hip_atomic_store(&((ULL*)An)[hoff], ((const ULL*)sHexH)[i],
                               __ATOMIC_RELAXED, __HIP_MEMORY_SCOPE_AGENT);
        } else if (threadIdx.x < 128) {
            if (l < 3) {
                unsigned short* Anx = apack + (size_t)((l + 1) * 2 + (t & 1)) * 32768;
                int ooff = ((bi >> 2) * 2 + (cbe >> 4)) * 128 + lanecode;
                __hip_atomic_store(&((ULL*)Anx)[ooff], ((const ULL*)sHexO)[i],
                                   __ATOMIC_RELAXED, __HIP_MEMORY_SCOPE_AGENT);
            } else {
                // fragment-packed classifier A-operand (plain store; kernel-end flush)
                int ulidx = ((((cbe * 16 + (bi >> 2)) * 4 + (t >> 4)) * 64 +
                             ((t & 15) | ((bi & 3) << 4))) * 2) + jh;
                ((ULL*)seqOut)[ulidx] = ((const ULL*)sHexO)[i];
            }
        }

        // own stores ack'd at coherence point, then publish flag = t+1
        asm volatile("s_waitcnt vmcnt(0)" ::: "memory");
        __syncthreads();
        if (threadIdx.x == 0)
            __hip_atomic_store(&flags[(l * 64 + bi) * 16], (unsigned)(t + 1),
                               __ATOMIC_RELAXED, __HIP_MEMORY_SCOPE_AGENT);
    }
}

// ---------------- fused classifier + log_softmax over T, packed operands ----------------
// 2 batches per block: vt = blk>>4, b in {2bp, 2bp+1}. Halves W_cls read traffic.
// Non-temporal output stores (f32x4 ext-vector: float4 class type is rejected by
// __builtin_nontemporal_store — r15 compile fix).
__global__ __launch_bounds__(256) void k_cls(
    const unsigned short* __restrict__ Ap,   // [32][16][4][64][8] packed seq
    const unsigned short* __restrict__ Wp,   // [250][4][2][16][64][8] packed W_cls
    float* __restrict__ out) {               // [B][T][V]
    int bp = blockIdx.x & 15;
    int vt = blockIdx.x >> 4;
    int wave = threadIdx.x >> 6;
    int lane = threadIdx.x & 63;

    __shared__ float sL[64 * 132];   // padded stride 132 (33 KB)

    const unsigned short* abase = Ap + (size_t)(bp * 2) * 32768 + lane * 8;
    const unsigned short* wbase = Wp + (size_t)(vt * 4 + wave) * 16384 + lane * 8;

    f32x4 acc[2][4][2];
    #pragma unroll
    for (int s = 0; s < 2; ++s)
        #pragma unroll
        for (int i = 0; i < 4; ++i)
            #pragma unroll
            for (int j = 0; j < 2; ++j) acc[s][i][j] = (f32x4)(0.0f);

    for (int k0 = 0; k0 < 16; ++k0) {
        bf16x8 bb[2];
        #pragma unroll
        for (int ni = 0; ni < 2; ++ni)
            bb[ni] = *(const bf16x8*)(wbase + ni * 8192 + k0 * 512);
        #pragma unroll
        for (int s = 0; s < 2; ++s) {
            bf16x8 a[4];
            #pragma unroll
            for (int mi = 0; mi < 4; ++mi)
                a[mi] = *(const bf16x8*)(abase + s * 32768 + (k0 * 4 + mi) * 512);
            #pragma unroll
            for (int mi = 0; mi < 4; ++mi)
                #pragma unroll
                for (int ni = 0; ni < 2; ++ni)
                    acc[s][mi][ni] = __builtin_amdgcn_mfma_f32_16x16x32_bf16(
                        a[mi], bb[ni], acc[s][mi][ni], 0, 0, 0);
        }
    }

    #pragma unroll
    for (int s = 0; s < 2; ++s) {
        if (s) __syncthreads();   // WAR: previous pass's sL reads done before rewrite
        #pragma unroll
        for (int ni = 0; ni < 2; ++ni) {
            float m = -1e30f;
            #pragma unroll
            for (int mi = 0; mi < 4; ++mi)
                #pragma unroll
                for (int r = 0; r < 4; ++r) m = fmaxf(m, acc[s][mi][ni][r]);
            m = fmaxf(m, __shfl_xor(m, 16));
            m = fmaxf(m, __shfl_xor(m, 32));
            float sum = 0.f;
            #pragma unroll
            for (int mi = 0; mi < 4; ++mi)
                #pragma unroll
                for (int r = 0; r < 4; ++r) sum += expf(acc[s][mi][ni][r] - m);
            sum += __shfl_xor(sum, 16);
            sum += __shfl_xor(sum, 32);
            float logZ = m + logf(sum);
            int col = wave * 32 + ni * 16 + (lane & 15);
            #pragma unroll
            for (int mi = 0; mi < 4; ++mi) {
                #pragma unroll
                for (int r = 0; r < 4; ++r) {
                    int row = mi * 16 + (lane >> 4) * 4 + r;
                    sL[row * 132 + col] = acc[s][mi][ni][r] - logZ;
                }
            }
        }
        __syncthreads();

        float* obase = out + (size_t)(bp * 2 + s) * TSTEPS * VOCAB + vt * 128;
        #pragma unroll
        for (int it = 0; it < 8; ++it) {
            int idx = it * 256 + threadIdx.x;
            int row = idx >> 5, c4 = (idx & 31) * 4;
            f32x4 val = *(const f32x4*)(sL + row * 132 + c4);
            __builtin_nontemporal_store(val, (f32x4*)(obase + (size_t)row * VOCAB + c4));
        }
    }
}

extern "C" void kernel_launch(void* const* d_in, const int* in_sizes, int n_in,
                              void* d_out, int out_size, void* d_ws, size_t ws_size,
                              hipStream_t stream) {
    const int*   dec   = (const int*)d_in[1];
    const float* h0    = (const float*)d_in[2];
    const float* c0    = (const float*)d_in[3];
    const float* emb   = (const float*)d_in[4];
    const float* W_ih  = (const float*)d_in[5];
    const float* W_hh  = (const float*)d_in[6];
    const float* b_ih  = (const float*)d_in[7];
    const float* b_hh  = (const float*)d_in[8];
    const float* W_cls = (const float*)d_in[9];

    const int LBH = NLAYERS * BATCH * HDIM;           // 65536
    const size_t BTV = (size_t)BATCH * TSTEPS * VOCAB;

    char* ws = (char*)d_ws;
    size_t off = 0;
    auto alloc = [&](size_t bytes) -> void* {
        void* p = ws + off;
        off = (off + bytes + 255) & ~(size_t)255;
        return p;
    };
    unsigned short* wpack  = (unsigned short*)alloc((size_t)NLAYERS * 64 * 2 * 32 * 64 * 8 * 2);
    float*          bsum   = (float*)alloc((size_t)NLAYERS * 64 * 32 * 4);
    unsigned short* wpackC = (unsigned short*)alloc((size_t)VOCAB * HDIM * 2);
    float*          seqF   = (float*)alloc((size_t)TSTEPS * BATCH * HDIM * 4);
    unsigned short* seqBp  = (unsigned short*)alloc((size_t)TSTEPS * 16384 * 2);
    unsigned short* apack  = (unsigned short*)alloc((size_t)NLAYERS * 2 * 32768 * 2);
    float*          outF   = (float*)alloc((size_t)NLAYERS * 2 * BATCH * HDIM * 4);
    unsigned short* apackC = (unsigned short*)alloc((size_t)TSTEPS * BATCH * HDIM * 2);
    unsigned*       flags  = (unsigned*)alloc(16384);

    k_prep_all<<<12449, 256, 0, stream>>>(W_ih, W_hh, b_ih, b_hh, W_cls, emb, dec, h0,
                                          wpack, bsum, wpackC, seqF, seqBp, apack, flags);

    k_lstm<<<256, 256, 0, stream>>>(apack, wpack, bsum, seqBp, seqF, outF, apackC,
                                    c0,
                                    (float*)d_out + BTV,
                                    (float*)d_out + BTV + LBH,
                                    flags);

    k_cls<<<250 * 16, 256, 0, stream>>>(apackC, wpackC, (float*)d_out);
}

// Round 17
// 437.267 us; speedup vs baseline: 1.3692x; 1.0482x over previous
//
#include <hip/hip_runtime.h>
#include <math.h>

#define VOCAB 32000
#define HDIM  512
#define NLAYERS 4
#define BATCH 32
#define TSTEPS 64
typedef unsigned long long ULL;

typedef __attribute__((ext_vector_type(8))) short bf16x8;
typedef __attribute__((ext_vector_type(4))) float f32x4;

static __device__ __forceinline__ unsigned short f2b(float f) {
    union { float f; unsigned u; } v; v.f = f;
    return (unsigned short)((v.u + 0x7FFFu + ((v.u >> 16) & 1u)) >> 16);
}
static __device__ __forceinline__ float sigf(float x) { return 1.0f / (1.0f + __expf(-x)); }

// packed offset of element (m,k) in a [32 rows][1024 k] bf16 operand stored in
// MFMA-fragment order: [k0=k/32][mi=m/16][lane][8]
static __device__ __forceinline__ int apack_off(int m, int k) {
    int k0 = k >> 5, mi = m >> 4;
    int lane = (m & 15) | (((k >> 3) & 3) << 4);
    return ((k0 * 2 + mi) * 64 + lane) * 8 + (k & 7);
}

// ---------------- preps fused (prep_w removed: k_lstm now self-packs W). Ranges:
//   [0,8000)        prep_wcls   (one 8-elem chunk per thread, 2048000)
//   [8000,8064)     embed       (t = blk-8000)
//   [8064,8320)     inith       (65536 threads)
//   [8320,8352)     prep_bias   (8192 threads)
//   [8352]          flags zero  (4096 u32)
__global__ void k_prep_all(
    const float* __restrict__ b_ih, const float* __restrict__ b_hh,
    const float* __restrict__ W_cls, const float* __restrict__ emb,
    const int* __restrict__ dec, const float* __restrict__ h0,
    float* __restrict__ bs,
    unsigned short* __restrict__ wpC, float* __restrict__ seqF,
    unsigned short* __restrict__ seqBp, unsigned short* __restrict__ apack,
    unsigned* __restrict__ flags) {
    int blk = blockIdx.x;
    if (blk < 8000) {
        int idx8 = blk * 256 + threadIdx.x;   // 2048000 chunks
        int lane = idx8 & 63, k0 = (idx8 >> 6) & 15, ni = (idx8 >> 10) & 1;
        int w = (idx8 >> 11) & 3, vt = idx8 >> 13;
        int v = vt * 128 + w * 32 + ni * 16 + (lane & 15);
        int kb = k0 * 32 + ((lane >> 4) << 3);
        const float* src = W_cls + (size_t)v * 512 + kb;
        float4 f0 = *(const float4*)(src);
        float4 f1 = *(const float4*)(src + 4);
        bf16x8 u;
        u[0] = (short)f2b(f0.x); u[1] = (short)f2b(f0.y);
        u[2] = (short)f2b(f0.z); u[3] = (short)f2b(f0.w);
        u[4] = (short)f2b(f1.x); u[5] = (short)f2b(f1.y);
        u[6] = (short)f2b(f1.z); u[7] = (short)f2b(f1.w);
        *(bf16x8*)(wpC + (size_t)idx8 * 8) = u;
    } else if (blk < 8064) {
        int t = blk - 8000;
        for (int i = threadIdx.x; i < BATCH * HDIM; i += blockDim.x) {
            int b = i >> 9, e = i & 511;
            int tok = dec[b * TSTEPS + t];
            float v = emb[(size_t)tok * HDIM + e];
            seqF[((size_t)t * BATCH + b) * HDIM + e] = v;
            seqBp[(size_t)t * 16384 + apack_off(b, e)] = f2b(v);
        }
    } else if (blk < 8320) {
        int idx = (blk - 8064) * 256 + threadIdx.x;   // 65536
        int l = idx >> 14, b = (idx >> 9) & 31, d = idx & 511;
        apack[(size_t)(l * 2) * 32768 + apack_off(b, 512 + d)] =
            f2b(h0[((size_t)l * BATCH + b) * HDIM + d]);
    } else if (blk < 8352) {
        int idx = (blk - 8320) * 256 + threadIdx.x;
        if (idx < NLAYERS * 64 * 32) {
            int r = idx & 31, bi = (idx >> 5) & 63, l = idx >> 11;
            int j = (r & 3) * 512 + bi * 8 + (r >> 2);
            bs[idx] = b_ih[l * 2048 + j] + b_hh[l * 2048 + j];
        }
    } else {
        for (int i = threadIdx.x; i < 4096; i += 256) flags[i] = 0;
    }
}

// ---------------- persistent LSTM: fence-free flag pipeline ----------------
// Per-step protocol byte-identical to round 14 (measured 284us). Only the one-time
// startup changed: each block self-packs its W slice from W_ih/W_hh (decode identical
// to the old k_prep_w with l,bi fixed) — removes the prep_w dispatch + wpack buffer.
// r12/13 lesson: do NOT bundle per-step protocol tweaks.
__global__ __launch_bounds__(256, 1) void k_lstm(
    unsigned short* apack,                    // [4][2][32768] bf16 fragment-packed [inp|h]
    const float* __restrict__ W_ih,           // [4][2048][512] f32
    const float* __restrict__ W_hh,           // [4][2048][512] f32
    const float* __restrict__ bsum,
    const unsigned short* __restrict__ seqBp, // [64][16384] packed emb (read-only, cached)
    const float* __restrict__ seqF,           // [64][32][512] fp32 emb (residual for l=0)
    float* outF,                              // [4][2][32][512] fp32 residual exchange
    unsigned short* __restrict__ seqOut,      // [32][16][4][64][8] final layer out, packed
    const float* __restrict__ c0,
    float* __restrict__ outHT, float* __restrict__ outCT,
    unsigned* flags) {                        // [4][64] flags, 64B stride
    const int l = blockIdx.x >> 6, bi = blockIdx.x & 63;
    const int wave = threadIdx.x >> 6, lane = threadIdx.x & 63;
    const int mi = wave >> 1, ni = wave & 1;
    const int cb = threadIdx.x >> 3, dsl = threadIdx.x & 7;
    const int d = bi * 8 + dsl;

    __shared__ __align__(16) short sW[32768];    // 64 KB W slice
    __shared__ __align__(16) short sA[32768];    // 64 KB A staging
    __shared__ __align__(16) float sG[1024];     //  4 KB gates
    __shared__ __align__(16) short sHexH[512];   //  1 KB h export repack
    __shared__ __align__(16) short sHexO[512];   //  1 KB o export repack

    {   // self-pack stationary W slice -> LDS (once; covered by the first in-loop barrier)
        #pragma unroll 4
        for (int ii = 0; ii < 128; ++ii) {
            int idx = ii * 256 + threadIdx.x;          // [0, 32768)
            int sub = idx & 7, lane2 = (idx >> 3) & 63, k0 = (idx >> 9) & 31;
            int ni2 = idx >> 14;
            int r = ni2 * 16 + (lane2 & 15);
            int k = k0 * 32 + ((lane2 >> 4) << 3) + sub;
            int j = (r & 3) * 512 + bi * 8 + (r >> 2);
            float v = (k < 512) ? W_ih[((size_t)l * 2048 + j) * 512 + k]
                                : W_hh[((size_t)l * 2048 + j) * 512 + (k - 512)];
            sW[idx] = (short)f2b(v);
        }
    }
    float4 bias = *(const float4*)(bsum + blockIdx.x * 32 + dsl * 4);
    float c = c0[((size_t)l * BATCH + cb) * HDIM + d];

    unsigned short* A0 = apack + (size_t)(l * 2 + 0) * 32768;
    unsigned short* A1 = apack + (size_t)(l * 2 + 1) * 32768;

    for (int t = 0; t < TSTEPS; ++t) {
        // ---- layer 0: prestage static emb inp-half (no flag dependency) ----
        if (l == 0) {
            const unsigned short* sp = seqBp + (size_t)t * 16384;
            #pragma unroll
            for (int i = 0; i < 8; ++i) {
                int off = (i * 256 + threadIdx.x) * 8;
                *(bf16x8*)(sA + off) = *(const bf16x8*)(sp + off);
            }
        }

        // ---- flow control: 3 waves spin per-lane on per-producer flags ----
        if (wave == 0 && t > 0) {                    // own layer finished step t-1
            const unsigned* fp = flags + (l * 64 + lane) * 16;
            while (__hip_atomic_load(fp, __ATOMIC_RELAXED, __HIP_MEMORY_SCOPE_AGENT)
                   < (unsigned)t)
                __builtin_amdgcn_s_sleep(1);
        }
        if (wave == 1 && l > 0) {                    // upstream finished step t
            const unsigned* fp = flags + ((l - 1) * 64 + lane) * 16;
            while (__hip_atomic_load(fp, __ATOMIC_RELAXED, __HIP_MEMORY_SCOPE_AGENT)
                   < (unsigned)(t + 1))
                __builtin_amdgcn_s_sleep(1);
        }
        if (wave == 2 && l < 3 && t > 0) {           // downstream consumed parity buffer
            const unsigned* fp = flags + ((l + 1) * 64 + lane) * 16;
            while (__hip_atomic_load(fp, __ATOMIC_RELAXED, __HIP_MEMORY_SCOPE_AGENT)
                   < (unsigned)(t - 1))
                __builtin_amdgcn_s_sleep(1);
        }
        __syncthreads();

        // ---- residual input: fp32, issued early to hide latency ----
        float inpf;
        if (l == 0) inpf = seqF[((size_t)t * BATCH + cb) * HDIM + d];
        else inpf = __hip_atomic_load(&outF[(size_t)((l * 2 + (t & 1)) * BATCH + cb) * HDIM + d],
                                      __ATOMIC_RELAXED, __HIP_MEMORY_SCOPE_AGENT);

        // ---- stage A(l, t&1) -> LDS via 8B coherence-point loads (batched) ----
        const unsigned short* Ab = (t & 1) ? A1 : A0;
        const ULL* Abu = (const ULL*)Ab;
        ULL* sAu = (ULL*)sA;
        if (l == 0) {
            ULL tmp[16];
            #pragma unroll
            for (int i = 0; i < 16; ++i)           // h half only (inp prestaged)
                tmp[i] = __hip_atomic_load(&Abu[(16 + i) * 256 + threadIdx.x],
                                           __ATOMIC_RELAXED, __HIP_MEMORY_SCOPE_AGENT);
            #pragma unroll
            for (int i = 0; i < 16; ++i)
                sAu[(16 + i) * 256 + threadIdx.x] = tmp[i];
        } else {
            ULL tmp[32];
            #pragma unroll
            for (int i = 0; i < 32; ++i)
                tmp[i] = __hip_atomic_load(&Abu[i * 256 + threadIdx.x],
                                           __ATOMIC_RELAXED, __HIP_MEMORY_SCOPE_AGENT);
            #pragma unroll
            for (int i = 0; i < 32; ++i)
                sAu[i * 256 + threadIdx.x] = tmp[i];
        }
        __syncthreads();

        // ---- gates = A @ Wslice^T (each wave one 16x16 tile, K=1024) ----
        f32x4 acc = {0.f, 0.f, 0.f, 0.f};
        const short* abase = sA + mi * 512 + lane * 8;
        const short* wbase = sW + ni * 16384 + lane * 8;
        #pragma unroll
        for (int k0 = 0; k0 < 32; ++k0)
            acc = __builtin_amdgcn_mfma_f32_16x16x32_bf16(
                *(const bf16x8*)(abase + k0 * 1024),
                *(const bf16x8*)(wbase + k0 * 512), acc, 0, 0, 0);

        int gb = mi * 16 + (lane >> 4) * 4;
        int gr = ni * 16 + (lane & 15);
        #pragma unroll
        for (int r = 0; r < 4; ++r) sG[(gb + r) * 32 + gr] = acc[r];
        __syncthreads();

        // ---- cell update (thread owns (cb, d)) ----
        float4 g4 = *(const float4*)(sG + cb * 32 + dsl * 4);
        float gi = g4.x + bias.x, gf = g4.y + bias.y;
        float gg = g4.z + bias.z, go = g4.w + bias.w;
        float ci = sigf(gf) * c + sigf(gi) * tanhf(gg);
        float hi = sigf(go) * tanhf(ci);
        c = ci;
        float o = hi + inpf;

        sHexH[threadIdx.x] = f2b(hi);
        sHexO[threadIdx.x] = f2b(o);
        if (l < 3)    // fp32 residual: agent-scope store straight to coherence point
            __hip_atomic_store(&outF[(size_t)(((l + 1) * 2 + (t & 1)) * BATCH + cb) * HDIM + d],
                               o, __ATOMIC_RELAXED, __HIP_MEMORY_SCOPE_AGENT);
        if (t == TSTEPS - 1) {
            outHT[((size_t)l * BATCH + cb) * HDIM + d] = hi;
            outCT[((size_t)l * BATCH + cb) * HDIM + d] = ci;
        }
        __syncthreads();

        // ---- export: coalesced 8B agent-scope stores ----
        unsigned short* An = ((t + 1) & 1) ? A1 : A0;
        int i = threadIdx.x & 63, cbe = i >> 1, jh = i & 1;
        int lanecode = ((cbe & 15) | ((bi & 3) << 4)) * 2 + jh;
        if (threadIdx.x < 64) {
            int hoff = ((16 + (bi >> 2)) * 2 + (cbe >> 4)) * 128 + lanecode;
            __hip_atomic_store(&((ULL*)An)[hoff], ((const ULL*)sHexH)[i],
                               __ATOMIC_RELAXED, __HIP_MEMORY_SCOPE_AGENT);
        } else if (threadIdx.x < 128) {
            if (l < 3) {
                unsigned short* Anx = apack + (size_t)((l + 1) * 2 + (t & 1)) * 32768;
                int ooff = ((bi >> 2) * 2 + (cbe >> 4)) * 128 + lanecode;
                __hip_atomic_store(&((ULL*)Anx)[ooff], ((const ULL*)sHexO)[i],
                                   __ATOMIC_RELAXED, __HIP_MEMORY_SCOPE_AGENT);
            } else {
                // fragment-packed classifier A-operand (plain store; kernel-end flush)
                int ulidx = ((((cbe * 16 + (bi >> 2)) * 4 + (t >> 4)) * 64 +
                             ((t & 15) | ((bi & 3) << 4))) * 2) + jh;
                ((ULL*)seqOut)[ulidx] = ((const ULL*)sHexO)[i];
            }
        }

        // own stores ack'd at coherence point, then publish flag = t+1
        asm volatile("s_waitcnt vmcnt(0)" ::: "memory");
        __syncthreads();
        if (threadIdx.x == 0)
            __hip_atomic_store(&flags[(l * 64 + bi) * 16], (unsigned)(t + 1),
                               __ATOMIC_RELAXED, __HIP_MEMORY_SCOPE_AGENT);
    }
}

// ---------------- fused classifier + log_softmax over T, packed operands ----------------
// 2 batches per block (verified r16) + XCD-grouping swizzle: all 16 bp-blocks of a vt
// land on one XCD so each W tile is fetched into exactly one L2.
__global__ __launch_bounds__(256) void k_cls(
    const unsigned short* __restrict__ Ap,   // [32][16][4][64][8] packed seq
    const unsigned short* __restrict__ Wp,   // [250][4][2][16][64][8] packed W_cls
    float* __restrict__ out) {               // [B][T][V]
    int bid = blockIdx.x;                    // 4000
    int u = (bid & 7) * 500 + (bid >> 3);    // consecutive u -> same XCD
    int bp = u & 15;
    int vt = u >> 4;
    int wave = threadIdx.x >> 6;
    int lane = threadIdx.x & 63;

    __shared__ float sL[64 * 132];   // padded stride 132 (33 KB)

    const unsigned short* abase = Ap + (size_t)(bp * 2) * 32768 + lane * 8;
    const unsigned short* wbase = Wp + (size_t)(vt * 4 + wave) * 16384 + lane * 8;

    f32x4 acc[2][4][2];
    #pragma unroll
    for (int s = 0; s < 2; ++s)
        #pragma unroll
        for (int i = 0; i < 4; ++i)
            #pragma unroll
            for (int j = 0; j < 2; ++j) acc[s][i][j] = (f32x4)(0.0f);

    for (int k0 = 0; k0 < 16; ++k0) {
        bf16x8 bb[2];
        #pragma unroll
        for (int ni = 0; ni < 2; ++ni)
            bb[ni] = *(const bf16x8*)(wbase + ni * 8192 + k0 * 512);
        #pragma unroll
        for (int s = 0; s < 2; ++s) {
            bf16x8 a[4];
            #pragma unroll
            for (int mi = 0; mi < 4; ++mi)
                a[mi] = *(const bf16x8*)(abase + s * 32768 + (k0 * 4 + mi) * 512);
            #pragma unroll
            for (int mi = 0; mi < 4; ++mi)
                #pragma unroll
                for (int ni = 0; ni < 2; ++ni)
                    acc[s][mi][ni] = __builtin_amdgcn_mfma_f32_16x16x32_bf16(
                        a[mi], bb[ni], acc[s][mi][ni], 0, 0, 0);
        }
    }

    #pragma unroll
    for (int s = 0; s < 2; ++s) {
        if (s) __syncthreads();   // WAR: previous pass's sL reads done before rewrite
        #pragma unroll
        for (int ni = 0; ni < 2; ++ni) {
            float m = -1e30f;
            #pragma unroll
            for (int mi = 0; mi < 4; ++mi)
                #pragma unroll
                for (int r = 0; r < 4; ++r) m = fmaxf(m, acc[s][mi][ni][r]);
            m = fmaxf(m, __shfl_xor(m, 16));
            m = fmaxf(m, __shfl_xor(m, 32));
            float sum = 0.f;
            #pragma unroll
            for (int mi = 0; mi < 4; ++mi)
                #pragma unroll
                for (int r = 0; r < 4; ++r) sum += expf(acc[s][mi][ni][r] - m);
            sum += __shfl_xor(sum, 16);
            sum += __shfl_xor(sum, 32);
            float logZ = m + logf(sum);
            int col = wave * 32 + ni * 16 + (lane & 15);
            #pragma unroll
            for (int mi = 0; mi < 4; ++mi) {
                #pragma unroll
                for (int r = 0; r < 4; ++r) {
                    int row = mi * 16 + (lane >> 4) * 4 + r;
                    sL[row * 132 + col] = acc[s][mi][ni][r] - logZ;
                }
            }
        }
        __syncthreads();

        float* obase = out + (size_t)(bp * 2 + s) * TSTEPS * VOCAB + vt * 128;
        #pragma unroll
        for (int it = 0; it < 8; ++it) {
            int idx = it * 256 + threadIdx.x;
            int row = idx >> 5, c4 = (idx & 31) * 4;
            f32x4 val = *(const f32x4*)(sL + row * 132 + c4);
            __builtin_nontemporal_store(val, (f32x4*)(obase + (size_t)row * VOCAB + c4));
        }
    }
}

extern "C" void kernel_launch(void* const* d_in, const int* in_sizes, int n_in,
                              void* d_out, int out_size, void* d_ws, size_t ws_size,
                              hipStream_t stream) {
    const int*   dec   = (const int*)d_in[1];
    const float* h0    = (const float*)d_in[2];
    const float* c0    = (const float*)d_in[3];
    const float* emb   = (const float*)d_in[4];
    const float* W_ih  = (const float*)d_in[5];
    const float* W_hh  = (const float*)d_in[6];
    const float* b_ih  = (const float*)d_in[7];
    const float* b_hh  = (const float*)d_in[8];
    const float* W_cls = (const float*)d_in[9];

    const int LBH = NLAYERS * BATCH * HDIM;           // 65536
    const size_t BTV = (size_t)BATCH * TSTEPS * VOCAB;

    char* ws = (char*)d_ws;
    size_t off = 0;
    auto alloc = [&](size_t bytes) -> void* {
        void* p = ws + off;
        off = (off + bytes + 255) & ~(size_t)255;
        return p;
    };
    float*          bsum   = (float*)alloc((size_t)NLAYERS * 64 * 32 * 4);
    unsigned short* wpackC = (unsigned short*)alloc((size_t)VOCAB * HDIM * 2);
    float*          seqF   = (float*)alloc((size_t)TSTEPS * BATCH * HDIM * 4);
    unsigned short* seqBp  = (unsigned short*)alloc((size_t)TSTEPS * 16384 * 2);
    unsigned short* apack  = (unsigned short*)alloc((size_t)NLAYERS * 2 * 32768 * 2);
    float*          outF   = (float*)alloc((size_t)NLAYERS * 2 * BATCH * HDIM * 4);
    unsigned short* apackC = (unsigned short*)alloc((size_t)TSTEPS * BATCH * HDIM * 2);
    unsigned*       flags  = (unsigned*)alloc(16384);

    k_prep_all<<<8353, 256, 0, stream>>>(b_ih, b_hh, W_cls, emb, dec, h0,
                                         bsum, wpackC, seqF, seqBp, apack, flags);

    k_lstm<<<256, 256, 0, stream>>>(apack, W_ih, W_hh, bsum, seqBp, seqF, outF, apackC,
                                    c0,
                                    (float*)d_out + BTV,
                                    (float*)d_out + BTV + LBH,
                                    flags);

    k_cls<<<250 * 16, 256, 0, stream>>>(apackC, wpackC, (float*)d_out);
}